// Round 1
// baseline (1188.128 us; speedup 1.0000x reference)
//
#include <hip/hip_runtime.h>

#define N_SEQ 2048
#define M_FFT 4096
#define D1    1536
#define NH    8
#define HD    192
#define ED    512

enum { ACT_NONE = 0, ACT_SILU = 1 };
enum { OUT_NORMAL = 0, OUT_TRANS = 1, OUT_VT = 2 };

// ---------------------------------------------------------------------------
// Generic fp32 tiled GEMM: C = act(A(MxK) @ Bw(NcxK)^T + bias)
// optional elementwise A2 gate (A_eff = A*A2), three output layouts.
// 64x64 tile, 256 threads, 4x4 per thread, K-tile 16. All dims divide tiles.
// ---------------------------------------------------------------------------
__global__ __launch_bounds__(256) void gemm_kernel(
    const float* __restrict__ A, const float* __restrict__ A2,
    const float* __restrict__ Bw, const float* __restrict__ bias,
    float* __restrict__ C, int M, int Nc, int K, int act, int outmode)
{
    __shared__ float As[16][68];   // +4 pad keeps 16B alignment, avoids conflicts
    __shared__ float Bs[16][68];
    const int tid  = threadIdx.x;
    const int row0 = blockIdx.y * 64;
    const int col0 = blockIdx.x * 64;
    const int tx   = tid & 15;
    const int ty   = tid >> 4;

    float acc[4][4] = {};

    const int kl = tid & 15;   // k within tile
    const int ml = tid >> 4;   // row/col group base

    for (int k0 = 0; k0 < K; k0 += 16) {
        #pragma unroll
        for (int l = 0; l < 4; ++l) {
            int mm = ml + l * 16;
            float a = A[(size_t)(row0 + mm) * K + k0 + kl];
            if (A2) a *= A2[(size_t)(row0 + mm) * K + k0 + kl];
            As[kl][mm] = a;
        }
        #pragma unroll
        for (int l = 0; l < 4; ++l) {
            int nn = ml + l * 16;
            Bs[kl][nn] = Bw[(size_t)(col0 + nn) * K + k0 + kl];
        }
        __syncthreads();
        #pragma unroll
        for (int k = 0; k < 16; ++k) {
            float a[4], b[4];
            #pragma unroll
            for (int i = 0; i < 4; ++i) a[i] = As[k][ty * 4 + i];
            #pragma unroll
            for (int j = 0; j < 4; ++j) b[j] = Bs[k][tx * 4 + j];
            #pragma unroll
            for (int i = 0; i < 4; ++i)
                #pragma unroll
                for (int j = 0; j < 4; ++j)
                    acc[i][j] += a[i] * b[j];
        }
        __syncthreads();
    }

    #pragma unroll
    for (int i = 0; i < 4; ++i) {
        int r = row0 + ty * 4 + i;
        #pragma unroll
        for (int j = 0; j < 4; ++j) {
            int c = col0 + tx * 4 + j;
            float val = acc[i][j] + bias[c];
            if (act == ACT_SILU) val = val / (1.0f + __expf(-val));
            if (outmode == OUT_NORMAL) {
                C[(size_t)r * Nc + c] = val;
            } else if (outmode == OUT_TRANS) {
                C[(size_t)c * M + r] = val;           // a_t[c][r]
            } else {                                   // OUT_VT: v_t[b][c][s]
                int b = r >> 11, s = r & 2047;
                C[((size_t)(b * D1 + c)) * N_SEQ + s] = val;
            }
        }
    }
}

// ---------------------------------------------------------------------------
// RPE input layer: h0[j,c] = idx(j) * Wp[c] + bp[c]; idx per reference
// ---------------------------------------------------------------------------
__global__ __launch_bounds__(256) void rpe_in_kernel(
    const float* __restrict__ Wp, const float* __restrict__ bp,
    float* __restrict__ h0)
{
    int j = blockIdx.x;
    float idxv = (j < N_SEQ) ? (float)j
                             : (j == N_SEQ ? 0.0f : (float)(j - 2 * N_SEQ));
    for (int c = threadIdx.x; c < ED; c += 256)
        h0[(size_t)j * ED + c] = idxv * Wp[c] + bp[c];
}

// ---------------------------------------------------------------------------
// g = relu(srms(h)) over rows of length 512
// ---------------------------------------------------------------------------
__global__ __launch_bounds__(256) void srms_relu_kernel(
    const float* __restrict__ in, float* __restrict__ out)
{
    const int row = blockIdx.x;
    const int tid = threadIdx.x;
    const float* p = in + (size_t)row * ED;

    float ss = 0.0f;
    for (int i = tid; i < ED; i += 256) { float x = p[i]; ss += x * x; }
    #pragma unroll
    for (int off = 32; off > 0; off >>= 1) ss += __shfl_down(ss, off, 64);
    __shared__ float red[4];
    if ((tid & 63) == 0) red[tid >> 6] = ss;
    __syncthreads();
    float tot = red[0] + red[1] + red[2] + red[3];
    // rms = ||h|| / sqrt(512);  scale = 1/(rms + 1e-8)
    float scale = 1.0f / (sqrtf(tot) * 0.04419417382415922f + 1e-8f);
    for (int i = tid; i < ED; i += 256)
        out[(size_t)row * ED + i] = fmaxf(p[i] * scale, 0.0f);
}

// ---------------------------------------------------------------------------
// FFT helpers: radix-2 in LDS, 4096 points, 256 threads.
// Forward: DIF (natural in -> bit-reversed out). Inverse: DIT (bitrev -> nat).
// tw[k] = exp(-2*pi*i*k/4096), k in [0,2048)
// ---------------------------------------------------------------------------
__device__ inline void build_tw(float2* tw, int tid)
{
    for (int k = tid; k < 2048; k += 256) {
        float ang = -6.283185307179586f * (float)k * (1.0f / 4096.0f);
        float s, c;
        __sincosf(ang, &s, &c);
        tw[k] = make_float2(c, s);
    }
}

__device__ inline void fft_fwd_dif(float2* d, const float2* tw, int tid)
{
    for (int sl = 11; sl >= 0; --sl) {
        const int len = 1 << sl;
        __syncthreads();
        for (int b = tid; b < 2048; b += 256) {
            int pos = b & (len - 1);
            int i0  = ((b >> sl) << (sl + 1)) + pos;
            int i1  = i0 + len;
            float2 u = d[i0], t = d[i1];
            float2 w = tw[pos << (11 - sl)];
            float dx = u.x - t.x, dy = u.y - t.y;
            d[i0] = make_float2(u.x + t.x, u.y + t.y);
            d[i1] = make_float2(dx * w.x - dy * w.y, dx * w.y + dy * w.x);
        }
    }
    __syncthreads();
}

__device__ inline void fft_inv_dit(float2* d, const float2* tw, int tid)
{
    for (int sl = 0; sl <= 11; ++sl) {
        const int len = 1 << sl;
        __syncthreads();
        for (int b = tid; b < 2048; b += 256) {
            int pos = b & (len - 1);
            int i0  = ((b >> sl) << (sl + 1)) + pos;
            int i1  = i0 + len;
            float2 u = d[i0], t0 = d[i1];
            float2 w = tw[pos << (11 - sl)];      // use conj(w) for inverse
            float tx = t0.x * w.x + t0.y * w.y;
            float ty = t0.y * w.x - t0.x * w.y;
            d[i0] = make_float2(u.x + tx, u.y + ty);
            d[i1] = make_float2(u.x - tx, u.y - ty);
        }
    }
    __syncthreads();
}

// ---------------------------------------------------------------------------
// F1: forward FFT of packed RPE kernel pairs -> Wspec (bit-reversed order)
// grid: 768 = 8 heads * 96 dpairs
// ---------------------------------------------------------------------------
__global__ __launch_bounds__(256) void fft_a_kernel(
    const float* __restrict__ a_t, float2* __restrict__ Wspec)
{
    __shared__ float2 data[4096];
    __shared__ float2 tw[2048];
    const int tid = threadIdx.x;
    const int h = blockIdx.x / 96, dp = blockIdx.x % 96;

    const float* r0 = a_t + ((size_t)(h * HD + 2 * dp)) * M_FFT;
    const float* r1 = r0 + M_FFT;

    build_tw(tw, tid);
    for (int j = tid; j < 4096; j += 256) data[j] = make_float2(r0[j], r1[j]);
    fft_fwd_dif(data, tw, tid);

    float2* outrow = Wspec + (size_t)blockIdx.x * 4096;
    for (int j = tid; j < 4096; j += 256) outrow[j] = data[j];
}

// ---------------------------------------------------------------------------
// F2: FFT(v pair) * A-spectrum (unpacked via conj symmetry), inverse FFT,
// write conv[b][t][c]. grid: 3072 = B * 8 * 96
// ---------------------------------------------------------------------------
__global__ __launch_bounds__(256) void fft_conv_kernel(
    const float* __restrict__ v_t, const float2* __restrict__ Wspec,
    float* __restrict__ conv)
{
    __shared__ float2 data[4096];
    __shared__ float2 tw[2048];
    const int tid = threadIdx.x;
    const int bx = blockIdx.x;
    const int b  = bx / 768;
    const int r  = bx % 768;
    const int h  = r / 96, dp = r % 96;

    const float* z0 = v_t + ((size_t)(b * D1 + h * HD + 2 * dp)) * N_SEQ;
    const float* z1 = z0 + N_SEQ;

    build_tw(tw, tid);
    for (int s = tid; s < 2048; s += 256) data[s] = make_float2(z0[s], z1[s]);
    for (int s = 2048 + tid; s < 4096; s += 256) data[s] = make_float2(0.f, 0.f);

    fft_fwd_dif(data, tw, tid);

    const float2* Wrow = Wspec + (size_t)r * 4096;
    for (int k = tid; k <= 2048; k += 256) {
        int km = (4096 - k) & 4095;
        int p1 = __brev((unsigned)k)  >> 20;   // 12-bit bit-reverse
        int p2 = __brev((unsigned)km) >> 20;
        float2 Zk = data[p1], Zm = data[p2];
        float2 Wk = Wrow[p1], Wm = Wrow[p2];
        // unpack two real spectra from packed complex FFT
        float2 V0 = make_float2(0.5f * (Zk.x + Zm.x), 0.5f * (Zk.y - Zm.y));
        float2 V1 = make_float2(0.5f * (Zk.y + Zm.y), 0.5f * (Zm.x - Zk.x));
        float2 A0 = make_float2(0.5f * (Wk.x + Wm.x), 0.5f * (Wk.y - Wm.y));
        float2 A1 = make_float2(0.5f * (Wk.y + Wm.y), 0.5f * (Wm.x - Wk.x));
        float2 P = make_float2(V0.x * A0.x - V0.y * A0.y, V0.x * A0.y + V0.y * A0.x);
        float2 Q = make_float2(V1.x * A1.x - V1.y * A1.y, V1.x * A1.y + V1.y * A1.x);
        // repack: Y = P + i*Q at bin k; Y = conj(P) + i*conj(Q) at bin m-k
        data[p1] = make_float2(P.x - Q.y, P.y + Q.x);
        if (k != 0 && k != 2048)
            data[p2] = make_float2(P.x + Q.y, Q.x - P.y);
    }

    fft_inv_dit(data, tw, tid);

    const float inv_m = 1.0f / 4096.0f;
    for (int t = tid; t < 2048; t += 256) {
        float2 y = data[t];
        size_t base = ((size_t)(b * N_SEQ + t)) * D1 + h * HD + 2 * dp;
        conv[base]     = y.x * inv_m;
        conv[base + 1] = y.y * inv_m;
    }
}

// ---------------------------------------------------------------------------
extern "C" void kernel_launch(void* const* d_in, const int* in_sizes, int n_in,
                              void* d_out, int out_size, void* d_ws, size_t ws_size,
                              hipStream_t stream)
{
    const float* x  = (const float*)d_in[0];
    const float* Wu = (const float*)d_in[1];
    const float* bu = (const float*)d_in[2];
    const float* Wv = (const float*)d_in[3];
    const float* bv = (const float*)d_in[4];
    const float* Wo = (const float*)d_in[5];
    const float* bo = (const float*)d_in[6];
    const float* Wp = (const float*)d_in[7];
    const float* bp = (const float*)d_in[8];
    const float* Wl = (const float*)d_in[9];
    const float* bl = (const float*)d_in[10];
    const float* Wr = (const float*)d_in[11];
    const float* br = (const float*)d_in[12];
    float* out = (float*)d_out;

    float* ws    = (float*)d_ws;
    float* u     = ws;                       // 8192*1536
    float* v_t   = u     + 12582912;         // [b][c][s]
    float* conv  = v_t   + 12582912;         // [b][t][c]
    float* a_t   = conv  + 12582912;         // [c][j]  (1536 x 4096)
    float* Wspec = a_t   + 6291456;          // 768 rows x 4096 float2
    float* h0    = Wspec + 6291456;          // 4096*512
    float* g     = h0    + 2097152;          // 4096*512

    dim3 blk(256);

    // u = silu(x @ Wu^T + bu)   (8192 x 1536)
    gemm_kernel<<<dim3(24, 128), blk, 0, stream>>>(
        x, nullptr, Wu, bu, u, 8192, D1, ED, ACT_SILU, OUT_NORMAL);
    // v = silu(x @ Wv^T + bv) -> transposed [b][c][s]
    gemm_kernel<<<dim3(24, 128), blk, 0, stream>>>(
        x, nullptr, Wv, bv, v_t, 8192, D1, ED, ACT_SILU, OUT_VT);

    // RPE MLP
    rpe_in_kernel<<<4096, blk, 0, stream>>>(Wp, bp, h0);
    srms_relu_kernel<<<4096, blk, 0, stream>>>(h0, g);
    for (int i = 0; i < 3; ++i) {
        gemm_kernel<<<dim3(8, 64), blk, 0, stream>>>(
            g, nullptr, Wl + (size_t)i * ED * ED, bl + (size_t)i * ED,
            h0, 4096, ED, ED, ACT_NONE, OUT_NORMAL);
        srms_relu_kernel<<<4096, blk, 0, stream>>>(h0, g);
    }
    // final RPE layer -> a_t transposed [c][j]
    gemm_kernel<<<dim3(24, 64), blk, 0, stream>>>(
        g, nullptr, Wr, br, a_t, 4096, D1, ED, ACT_NONE, OUT_TRANS);

    // FFT of RPE kernels
    fft_a_kernel<<<768, blk, 0, stream>>>(a_t, (float2*)Wspec);
    // FFT conv: v (*) a  -> conv[b][t][c]
    fft_conv_kernel<<<3072, blk, 0, stream>>>(v_t, (const float2*)Wspec, conv);

    // out = (u .* conv) @ Wo^T + bo   (8192 x 512)
    gemm_kernel<<<dim3(8, 128), blk, 0, stream>>>(
        u, conv, Wo, bo, out, 8192, ED, D1, ACT_NONE, OUT_NORMAL);
}

// Round 2
// 565.618 us; speedup vs baseline: 2.1006x; 2.1006x over previous
//
#include <hip/hip_runtime.h>

#define N_SEQ 2048
#define M_FFT 4096
#define D1    1536
#define NH    8
#define HD    192
#define ED    512

typedef __bf16 bf16;
typedef __bf16 bf16x8 __attribute__((ext_vector_type(8)));
typedef float  floatx4 __attribute__((ext_vector_type(4)));

enum { MODE_PLAIN = 0, MODE_SILU = 1, MODE_SILU_VT = 2, MODE_AT = 3 };

__device__ __forceinline__ void gload16(const void* g, void* l) {
    __builtin_amdgcn_global_load_lds(
        (const __attribute__((address_space(1))) void*)g,
        (__attribute__((address_space(3))) void*)l, 16, 0, 0);
}

// ---------------------------------------------------------------------------
// bf16 MFMA GEMM (m97 structure): C = epilogue(A(MxK) @ Bw(NcxK)^T + bias)
// 128x128 tile, 256 thr, per-wave 64x64 = 4x4 of 16x16x32 MFMA, BK=32.
// All dims are multiples of 128(M,Nc)/32(K).
// ---------------------------------------------------------------------------
template<int MODE>
__global__ __launch_bounds__(256) void gemm_bf16(
    const bf16* __restrict__ A, const bf16* __restrict__ Bw,
    const float* __restrict__ bias, float* __restrict__ C,
    int M, int Nc, int K)
{
    __shared__ __align__(16) bf16 As[128 * 32];
    __shared__ __align__(16) bf16 Bs[128 * 32];

    const int tid  = threadIdx.x;
    const int row0 = blockIdx.y * 128;
    const int col0 = blockIdx.x * 128;
    const int wid  = tid >> 6;
    const int lane = tid & 63;
    const int lm   = lane & 15;      // row/col within 16x16 tile
    const int lk   = lane >> 4;      // k-quad
    const int wm   = wid >> 1;       // wave row (0..1)
    const int wn   = wid & 1;        // wave col (0..1)
    const int ldrow  = tid >> 2;     // 0..63 staging row
    const int ldcol8 = (tid & 3) * 8;

    floatx4 acc[4][4] = {};

    const bf16* Ag = A  + ((size_t)(row0 + ldrow)) * K + ldcol8;
    const bf16* Bg = Bw + ((size_t)(col0 + ldrow)) * K + ldcol8;
    bf16* AsW = As + (wid * 16) * 32;
    bf16* BsW = Bs + (wid * 16) * 32;

    for (int k0 = 0; k0 < K; k0 += 32) {
        gload16(Ag + k0, AsW);
        gload16(Ag + (size_t)64 * K + k0, AsW + 64 * 32);
        gload16(Bg + k0, BsW);
        gload16(Bg + (size_t)64 * K + k0, BsW + 64 * 32);
        __syncthreads();

        bf16x8 af[4], bfr[4];
        #pragma unroll
        for (int mi = 0; mi < 4; ++mi)
            af[mi] = *(const bf16x8*)&As[(wm * 64 + mi * 16 + lm) * 32 + lk * 8];
        #pragma unroll
        for (int nj = 0; nj < 4; ++nj)
            bfr[nj] = *(const bf16x8*)&Bs[(wn * 64 + nj * 16 + lm) * 32 + lk * 8];
        #pragma unroll
        for (int mi = 0; mi < 4; ++mi)
            #pragma unroll
            for (int nj = 0; nj < 4; ++nj)
                acc[mi][nj] = __builtin_amdgcn_mfma_f32_16x16x32_bf16(
                    af[mi], bfr[nj], acc[mi][nj], 0, 0, 0);
        __syncthreads();
    }

    // C/D layout: col = lane&15, row = (lane>>4)*4 + r  [m89-verified]
    float bcol[4];
    #pragma unroll
    for (int nj = 0; nj < 4; ++nj)
        bcol[nj] = bias[col0 + wn * 64 + nj * 16 + lm];

    #pragma unroll
    for (int mi = 0; mi < 4; ++mi) {
        #pragma unroll
        for (int nj = 0; nj < 4; ++nj) {
            const int col = col0 + wn * 64 + nj * 16 + lm;
            #pragma unroll
            for (int r = 0; r < 4; ++r) {
                const int row = row0 + wm * 64 + mi * 16 + lk * 4 + r;
                float val = acc[mi][nj][r] + bcol[nj];
                if (MODE == MODE_SILU || MODE == MODE_SILU_VT)
                    val = val / (1.0f + __expf(-val));
                if (MODE == MODE_SILU_VT) {
                    int b = row >> 11, s = row & 2047;
                    C[((size_t)(b * D1 + col)) * N_SEQ + s] = val;
                } else if (MODE == MODE_AT) {
                    C[(size_t)col * M + row] = val;
                } else {
                    C[(size_t)row * Nc + col] = val;
                }
            }
        }
    }
}

// ---------------------------------------------------------------------------
// fp32 -> bf16 convert (n divisible by 4)
// ---------------------------------------------------------------------------
__global__ __launch_bounds__(256) void f2b_kernel(
    const float* __restrict__ in, bf16* __restrict__ out, int n)
{
    int i = (blockIdx.x * 256 + threadIdx.x) * 4;
    if (i >= n) return;
    float4 f = *(const float4*)(in + i);
    union { bf16 h[4]; short4 s; } u4;
    u4.h[0] = (bf16)f.x; u4.h[1] = (bf16)f.y;
    u4.h[2] = (bf16)f.z; u4.h[3] = (bf16)f.w;
    *(short4*)(out + i) = u4.s;
}

// ---------------------------------------------------------------------------
// RPE input layer: h0[j,c] = idx(j) * Wp[c] + bp[c]
// ---------------------------------------------------------------------------
__global__ __launch_bounds__(256) void rpe_in_kernel(
    const float* __restrict__ Wp, const float* __restrict__ bp,
    float* __restrict__ h0)
{
    int j = blockIdx.x;
    float idxv = (j < N_SEQ) ? (float)j
                             : (j == N_SEQ ? 0.0f : (float)(j - 2 * N_SEQ));
    for (int c = threadIdx.x; c < ED; c += 256)
        h0[(size_t)j * ED + c] = idxv * Wp[c] + bp[c];
}

// ---------------------------------------------------------------------------
// g = relu(srms(h)) -> bf16, rows of 512
// ---------------------------------------------------------------------------
__global__ __launch_bounds__(256) void srms_relu_kernel(
    const float* __restrict__ in, bf16* __restrict__ out)
{
    const int row = blockIdx.x;
    const int tid = threadIdx.x;
    const float* p = in + (size_t)row * ED;

    float ss = 0.0f;
    for (int i = tid; i < ED; i += 256) { float x = p[i]; ss += x * x; }
    #pragma unroll
    for (int off = 32; off > 0; off >>= 1) ss += __shfl_down(ss, off, 64);
    __shared__ float red[4];
    if ((tid & 63) == 0) red[tid >> 6] = ss;
    __syncthreads();
    float tot = red[0] + red[1] + red[2] + red[3];
    float scale = 1.0f / (sqrtf(tot) * 0.04419417382415922f + 1e-8f);
    for (int i = tid; i < ED; i += 256)
        out[(size_t)row * ED + i] = (bf16)fmaxf(p[i] * scale, 0.0f);
}

// ---------------------------------------------------------------------------
// FFT helpers: radix-2 in LDS, 4096 pts, 256 threads.
// ---------------------------------------------------------------------------
__device__ inline void build_tw(float2* tw, int tid)
{
    for (int k = tid; k < 2048; k += 256) {
        float ang = -6.283185307179586f * (float)k * (1.0f / 4096.0f);
        float s, c;
        __sincosf(ang, &s, &c);
        tw[k] = make_float2(c, s);
    }
}

__device__ inline void fft_fwd_dif(float2* d, const float2* tw, int tid)
{
    for (int sl = 11; sl >= 0; --sl) {
        const int len = 1 << sl;
        __syncthreads();
        for (int b = tid; b < 2048; b += 256) {
            int pos = b & (len - 1);
            int i0  = ((b >> sl) << (sl + 1)) + pos;
            int i1  = i0 + len;
            float2 u = d[i0], t = d[i1];
            float2 w = tw[pos << (11 - sl)];
            float dx = u.x - t.x, dy = u.y - t.y;
            d[i0] = make_float2(u.x + t.x, u.y + t.y);
            d[i1] = make_float2(dx * w.x - dy * w.y, dx * w.y + dy * w.x);
        }
    }
    __syncthreads();
}

__device__ inline void fft_inv_dit(float2* d, const float2* tw, int tid)
{
    for (int sl = 0; sl <= 11; ++sl) {
        const int len = 1 << sl;
        __syncthreads();
        for (int b = tid; b < 2048; b += 256) {
            int pos = b & (len - 1);
            int i0  = ((b >> sl) << (sl + 1)) + pos;
            int i1  = i0 + len;
            float2 u = d[i0], t0 = d[i1];
            float2 w = tw[pos << (11 - sl)];
            float tx = t0.x * w.x + t0.y * w.y;
            float ty = t0.y * w.x - t0.x * w.y;
            d[i0] = make_float2(u.x + tx, u.y + ty);
            d[i1] = make_float2(u.x - tx, u.y - ty);
        }
    }
    __syncthreads();
}

// ---------------------------------------------------------------------------
// F1: forward FFT of packed RPE kernel pairs -> Wspec (bit-reversed)
// ---------------------------------------------------------------------------
__global__ __launch_bounds__(256) void fft_a_kernel(
    const float* __restrict__ a_t, float2* __restrict__ Wspec)
{
    __shared__ float2 data[4096];
    __shared__ float2 tw[2048];
    const int tid = threadIdx.x;
    const int h = blockIdx.x / 96, dp = blockIdx.x % 96;

    const float* r0 = a_t + ((size_t)(h * HD + 2 * dp)) * M_FFT;
    const float* r1 = r0 + M_FFT;

    build_tw(tw, tid);
    for (int j = tid; j < 4096; j += 256) data[j] = make_float2(r0[j], r1[j]);
    fft_fwd_dif(data, tw, tid);

    float2* outrow = Wspec + (size_t)blockIdx.x * 4096;
    for (int j = tid; j < 4096; j += 256) outrow[j] = data[j];
}

// ---------------------------------------------------------------------------
// F2: FFT(v pair) * A-spectrum, inverse FFT, gate by u, write bf16 gated.
// ---------------------------------------------------------------------------
__global__ __launch_bounds__(256) void fft_conv_kernel(
    const float* __restrict__ v_t, const float2* __restrict__ Wspec,
    const float* __restrict__ ug, bf16* __restrict__ gated)
{
    __shared__ float2 data[4096];
    __shared__ float2 tw[2048];
    const int tid = threadIdx.x;
    const int bx = blockIdx.x;
    const int b  = bx / 768;
    const int r  = bx % 768;
    const int h  = r / 96, dp = r % 96;

    const float* z0 = v_t + ((size_t)(b * D1 + h * HD + 2 * dp)) * N_SEQ;
    const float* z1 = z0 + N_SEQ;

    build_tw(tw, tid);
    for (int s = tid; s < 2048; s += 256) data[s] = make_float2(z0[s], z1[s]);
    for (int s = 2048 + tid; s < 4096; s += 256) data[s] = make_float2(0.f, 0.f);

    fft_fwd_dif(data, tw, tid);

    const float2* Wrow = Wspec + (size_t)r * 4096;
    for (int k = tid; k <= 2048; k += 256) {
        int km = (4096 - k) & 4095;
        int p1 = __brev((unsigned)k)  >> 20;
        int p2 = __brev((unsigned)km) >> 20;
        float2 Zk = data[p1], Zm = data[p2];
        float2 Wk = Wrow[p1], Wm = Wrow[p2];
        float2 V0 = make_float2(0.5f * (Zk.x + Zm.x), 0.5f * (Zk.y - Zm.y));
        float2 V1 = make_float2(0.5f * (Zk.y + Zm.y), 0.5f * (Zm.x - Zk.x));
        float2 A0 = make_float2(0.5f * (Wk.x + Wm.x), 0.5f * (Wk.y - Wm.y));
        float2 A1 = make_float2(0.5f * (Wk.y + Wm.y), 0.5f * (Wm.x - Wk.x));
        float2 P = make_float2(V0.x * A0.x - V0.y * A0.y, V0.x * A0.y + V0.y * A0.x);
        float2 Q = make_float2(V1.x * A1.x - V1.y * A1.y, V1.x * A1.y + V1.y * A1.x);
        data[p1] = make_float2(P.x - Q.y, P.y + Q.x);
        if (k != 0 && k != 2048)
            data[p2] = make_float2(P.x + Q.y, Q.x - P.y);
    }

    fft_inv_dit(data, tw, tid);

    const float inv_m = 1.0f / 4096.0f;
    for (int t = tid; t < 2048; t += 256) {
        float2 y = data[t];
        size_t base = ((size_t)(b * N_SEQ + t)) * D1 + h * HD + 2 * dp;
        gated[base]     = (bf16)(y.x * inv_m * ug[base]);
        gated[base + 1] = (bf16)(y.y * inv_m * ug[base + 1]);
    }
}

// ---------------------------------------------------------------------------
extern "C" void kernel_launch(void* const* d_in, const int* in_sizes, int n_in,
                              void* d_out, int out_size, void* d_ws, size_t ws_size,
                              hipStream_t stream)
{
    const float* x  = (const float*)d_in[0];
    const float* Wu = (const float*)d_in[1];
    const float* bu = (const float*)d_in[2];
    const float* Wv = (const float*)d_in[3];
    const float* bv = (const float*)d_in[4];
    const float* Wo = (const float*)d_in[5];
    const float* bo = (const float*)d_in[6];
    const float* Wp = (const float*)d_in[7];
    const float* bp = (const float*)d_in[8];
    const float* Wl = (const float*)d_in[9];
    const float* bl = (const float*)d_in[10];
    const float* Wr = (const float*)d_in[11];
    const float* br = (const float*)d_in[12];
    float* out = (float*)d_out;

    float* ws    = (float*)d_ws;
    float* u     = ws;                       // 8192*1536 fp32
    float* v_t   = u     + 12582912;         // [b][c][s] fp32
    float* a_t   = v_t   + 12582912;         // [c][j] fp32 (1536 x 4096)
    float* Wspec = a_t   + 6291456;          // 768 x 4096 float2
    float* h0    = Wspec + 6291456;          // 4096*512 fp32
    bf16*  bfws  = (bf16*)(h0 + 2097152);
    bf16*  x_bf  = bfws;                     // 8192*512
    bf16*  Wu_bf = x_bf  + 4194304;          // 1536*512
    bf16*  Wv_bf = Wu_bf + 786432;
    bf16*  Wo_bf = Wv_bf + 786432;           // 512*1536
    bf16*  Wl_bf = Wo_bf + 786432;           // 3*512*512
    bf16*  Wr_bf = Wl_bf + 786432;           // 1536*512
    bf16*  g_bf  = Wr_bf + 786432;           // 4096*512
    bf16*  gated = g_bf  + 2097152;          // 8192*1536 (u .* conv)

    dim3 blk(256);

    // converts
    f2b_kernel<<<4194304 / 1024, blk, 0, stream>>>(x,  x_bf,  4194304);
    f2b_kernel<<<786432 / 1024, blk, 0, stream>>>(Wu, Wu_bf, 786432);
    f2b_kernel<<<786432 / 1024, blk, 0, stream>>>(Wv, Wv_bf, 786432);
    f2b_kernel<<<786432 / 1024, blk, 0, stream>>>(Wo, Wo_bf, 786432);
    f2b_kernel<<<786432 / 1024, blk, 0, stream>>>(Wl, Wl_bf, 786432);
    f2b_kernel<<<786432 / 1024, blk, 0, stream>>>(Wr, Wr_bf, 786432);

    // u = silu(x@Wu^T+bu); v = silu(x@Wv^T+bv) -> v_t[b][c][s]
    gemm_bf16<MODE_SILU><<<dim3(12, 64), blk, 0, stream>>>(
        x_bf, Wu_bf, bu, u, 8192, D1, ED);
    gemm_bf16<MODE_SILU_VT><<<dim3(12, 64), blk, 0, stream>>>(
        x_bf, Wv_bf, bv, v_t, 8192, D1, ED);

    // RPE MLP
    rpe_in_kernel<<<4096, blk, 0, stream>>>(Wp, bp, h0);
    srms_relu_kernel<<<4096, blk, 0, stream>>>(h0, g_bf);
    for (int i = 0; i < 3; ++i) {
        gemm_bf16<MODE_PLAIN><<<dim3(4, 32), blk, 0, stream>>>(
            g_bf, Wl_bf + (size_t)i * ED * ED, bl + (size_t)i * ED,
            h0, 4096, ED, ED);
        srms_relu_kernel<<<4096, blk, 0, stream>>>(h0, g_bf);
    }
    gemm_bf16<MODE_AT><<<dim3(12, 32), blk, 0, stream>>>(
        g_bf, Wr_bf, br, a_t, 4096, D1, ED);

    // FFT stage
    fft_a_kernel<<<768, blk, 0, stream>>>(a_t, (float2*)Wspec);
    fft_conv_kernel<<<3072, blk, 0, stream>>>(
        v_t, (const float2*)Wspec, u, gated);

    // out = gated @ Wo^T + bo
    gemm_bf16<MODE_PLAIN><<<dim3(4, 64), blk, 0, stream>>>(
        gated, Wo_bf, bo, out, 8192, ED, D1);
}

// Round 3
// 489.983 us; speedup vs baseline: 2.4248x; 1.1544x over previous
//
#include <hip/hip_runtime.h>

#define N_SEQ 2048
#define M_FFT 4096
#define D1    1536
#define NH    8
#define HD    192
#define ED    512

typedef __bf16 bf16;
typedef __bf16 bf16x8 __attribute__((ext_vector_type(8)));
typedef float  floatx4 __attribute__((ext_vector_type(4)));

enum { MODE_PLAIN = 0, MODE_SILU = 1, MODE_SILU_VT = 2, MODE_AT = 3 };

__device__ __forceinline__ void gload16(const void* g, void* l) {
    __builtin_amdgcn_global_load_lds(
        (const __attribute__((address_space(1))) void*)g,
        (__attribute__((address_space(3))) void*)l, 16, 0, 0);
}

// ---------------------------------------------------------------------------
// bf16 MFMA GEMM (m97 structure): C = epilogue(A(MxK) @ Bw(NcxK)^T + bias)
// ---------------------------------------------------------------------------
template<int MODE>
__global__ __launch_bounds__(256) void gemm_bf16(
    const bf16* __restrict__ A, const bf16* __restrict__ Bw,
    const float* __restrict__ bias, float* __restrict__ C,
    int M, int Nc, int K)
{
    __shared__ __align__(16) bf16 As[128 * 32];
    __shared__ __align__(16) bf16 Bs[128 * 32];

    const int tid  = threadIdx.x;
    const int row0 = blockIdx.y * 128;
    const int col0 = blockIdx.x * 128;
    const int wid  = tid >> 6;
    const int lane = tid & 63;
    const int lm   = lane & 15;
    const int lk   = lane >> 4;
    const int wm   = wid >> 1;
    const int wn   = wid & 1;
    const int ldrow  = tid >> 2;
    const int ldcol8 = (tid & 3) * 8;

    floatx4 acc[4][4] = {};

    const bf16* Ag = A  + ((size_t)(row0 + ldrow)) * K + ldcol8;
    const bf16* Bg = Bw + ((size_t)(col0 + ldrow)) * K + ldcol8;
    bf16* AsW = As + (wid * 16) * 32;
    bf16* BsW = Bs + (wid * 16) * 32;

    for (int k0 = 0; k0 < K; k0 += 32) {
        gload16(Ag + k0, AsW);
        gload16(Ag + (size_t)64 * K + k0, AsW + 64 * 32);
        gload16(Bg + k0, BsW);
        gload16(Bg + (size_t)64 * K + k0, BsW + 64 * 32);
        __syncthreads();

        bf16x8 af[4], bfr[4];
        #pragma unroll
        for (int mi = 0; mi < 4; ++mi)
            af[mi] = *(const bf16x8*)&As[(wm * 64 + mi * 16 + lm) * 32 + lk * 8];
        #pragma unroll
        for (int nj = 0; nj < 4; ++nj)
            bfr[nj] = *(const bf16x8*)&Bs[(wn * 64 + nj * 16 + lm) * 32 + lk * 8];
        #pragma unroll
        for (int mi = 0; mi < 4; ++mi)
            #pragma unroll
            for (int nj = 0; nj < 4; ++nj)
                acc[mi][nj] = __builtin_amdgcn_mfma_f32_16x16x32_bf16(
                    af[mi], bfr[nj], acc[mi][nj], 0, 0, 0);
        __syncthreads();
    }

    float bcol[4];
    #pragma unroll
    for (int nj = 0; nj < 4; ++nj)
        bcol[nj] = bias[col0 + wn * 64 + nj * 16 + lm];

    #pragma unroll
    for (int mi = 0; mi < 4; ++mi) {
        #pragma unroll
        for (int nj = 0; nj < 4; ++nj) {
            const int col = col0 + wn * 64 + nj * 16 + lm;
            #pragma unroll
            for (int r = 0; r < 4; ++r) {
                const int row = row0 + wm * 64 + mi * 16 + lk * 4 + r;
                float val = acc[mi][nj][r] + bcol[nj];
                if (MODE == MODE_SILU || MODE == MODE_SILU_VT)
                    val = val / (1.0f + __expf(-val));
                if (MODE == MODE_SILU_VT) {
                    int b = row >> 11, s = row & 2047;
                    C[((size_t)(b * D1 + col)) * N_SEQ + s] = val;
                } else if (MODE == MODE_AT) {
                    C[(size_t)col * M + row] = val;
                } else {
                    C[(size_t)row * Nc + col] = val;
                }
            }
        }
    }
}

// ---------------------------------------------------------------------------
__global__ __launch_bounds__(256) void f2b_kernel(
    const float* __restrict__ in, bf16* __restrict__ out, int n)
{
    int i = (blockIdx.x * 256 + threadIdx.x) * 4;
    if (i >= n) return;
    float4 f = *(const float4*)(in + i);
    union { bf16 h[4]; short4 s; } u4;
    u4.h[0] = (bf16)f.x; u4.h[1] = (bf16)f.y;
    u4.h[2] = (bf16)f.z; u4.h[3] = (bf16)f.w;
    *(short4*)(out + i) = u4.s;
}

__global__ __launch_bounds__(256) void rpe_in_kernel(
    const float* __restrict__ Wp, const float* __restrict__ bp,
    float* __restrict__ h0)
{
    int j = blockIdx.x;
    float idxv = (j < N_SEQ) ? (float)j
                             : (j == N_SEQ ? 0.0f : (float)(j - 2 * N_SEQ));
    for (int c = threadIdx.x; c < ED; c += 256)
        h0[(size_t)j * ED + c] = idxv * Wp[c] + bp[c];
}

__global__ __launch_bounds__(256) void srms_relu_kernel(
    const float* __restrict__ in, bf16* __restrict__ out)
{
    const int row = blockIdx.x;
    const int tid = threadIdx.x;
    const float* p = in + (size_t)row * ED;

    float ss = 0.0f;
    for (int i = tid; i < ED; i += 256) { float x = p[i]; ss += x * x; }
    #pragma unroll
    for (int off = 32; off > 0; off >>= 1) ss += __shfl_down(ss, off, 64);
    __shared__ float red[4];
    if ((tid & 63) == 0) red[tid >> 6] = ss;
    __syncthreads();
    float tot = red[0] + red[1] + red[2] + red[3];
    float scale = 1.0f / (sqrtf(tot) * 0.04419417382415922f + 1e-8f);
    for (int i = tid; i < ED; i += 256)
        out[(size_t)row * ED + i] = (bf16)fmaxf(p[i] * scale, 0.0f);
}

// ---------------------------------------------------------------------------
// Radix-16 FFT machinery. 4096 = 16^3, 256 threads x 16 complex in registers.
// LDS pad: i + (i>>4) + 2*(i>>8)  -> all stage strides hit b64 2-words/bank.
// Global scramble after forward = 12-bit bit-reversal (same as radix-2 ver).
// ---------------------------------------------------------------------------
#define FFT_LDS_SZ 4381   // pad(4095)+1

__device__ __forceinline__ int fpad(int i) { return i + (i >> 4) + 2 * (i >> 8); }

__device__ __forceinline__ float2 cmul(float2 a, float2 b) {
    return make_float2(a.x * b.x - a.y * b.y, a.x * b.y + a.y * b.x);
}
__device__ __forceinline__ float2 cadd(float2 a, float2 b) {
    return make_float2(a.x + b.x, a.y + b.y);
}
__device__ __forceinline__ float2 csub(float2 a, float2 b) {
    return make_float2(a.x - b.x, a.y - b.y);
}
__host__ __device__ constexpr int brev4(int t) {
    return ((t & 1) << 3) | ((t & 2) << 1) | ((t & 4) >> 1) | ((t & 8) >> 3);
}

template<bool FWD>
__device__ __forceinline__ void w16_tab(float2 w[8]) {
    const float sg = FWD ? -1.0f : 1.0f;
    const float C1 = 0.9238795325112867f, S1 = 0.3826834323650898f;
    const float C2 = 0.7071067811865476f;
    w[0] = make_float2( 1.f, 0.f);
    w[1] = make_float2( C1, sg * S1);
    w[2] = make_float2( C2, sg * C2);
    w[3] = make_float2( S1, sg * C1);
    w[4] = make_float2(0.f, sg * 1.f);
    w[5] = make_float2(-S1, sg * C1);
    w[6] = make_float2(-C2, sg * C2);
    w[7] = make_float2(-C1, sg * S1);
}

// forward 16-pt, natural in -> bitrev4 out (DIF)
__device__ __forceinline__ void fft16_dif(float2 x[16]) {
    float2 w[8]; w16_tab<true>(w);
    #pragma unroll
    for (int k = 0; k < 8; ++k) {
        float2 u = x[k], t = x[k + 8];
        x[k] = cadd(u, t); x[k + 8] = cmul(csub(u, t), w[k]);
    }
    #pragma unroll
    for (int b = 0; b < 16; b += 8)
        #pragma unroll
        for (int k = 0; k < 4; ++k) {
            float2 u = x[b + k], t = x[b + k + 4];
            x[b + k] = cadd(u, t); x[b + k + 4] = cmul(csub(u, t), w[2 * k]);
        }
    #pragma unroll
    for (int b = 0; b < 16; b += 4)
        #pragma unroll
        for (int k = 0; k < 2; ++k) {
            float2 u = x[b + k], t = x[b + k + 2];
            x[b + k] = cadd(u, t); x[b + k + 2] = cmul(csub(u, t), w[4 * k]);
        }
    #pragma unroll
    for (int b = 0; b < 16; b += 2) {
        float2 u = x[b], t = x[b + 1];
        x[b] = cadd(u, t); x[b + 1] = csub(u, t);
    }
}

// inverse 16-pt (conj twiddles), bitrev4 in -> natural out (DIT), scaled x16
__device__ __forceinline__ void fft16_dit_inv(float2 x[16]) {
    float2 w[8]; w16_tab<false>(w);
    #pragma unroll
    for (int b = 0; b < 16; b += 2) {
        float2 u = x[b], t = x[b + 1];
        x[b] = cadd(u, t); x[b + 1] = csub(u, t);
    }
    #pragma unroll
    for (int b = 0; b < 16; b += 4)
        #pragma unroll
        for (int k = 0; k < 2; ++k) {
            float2 u = x[b + k], t = cmul(x[b + k + 2], w[4 * k]);
            x[b + k] = cadd(u, t); x[b + k + 2] = csub(u, t);
        }
    #pragma unroll
    for (int b = 0; b < 16; b += 8)
        #pragma unroll
        for (int k = 0; k < 4; ++k) {
            float2 u = x[b + k], t = cmul(x[b + k + 4], w[2 * k]);
            x[b + k] = cadd(u, t); x[b + k + 4] = csub(u, t);
        }
    #pragma unroll
    for (int k = 0; k < 8; ++k) {
        float2 u = x[k], t = cmul(x[k + 8], w[k]);
        x[k] = cadd(u, t); x[k + 8] = csub(u, t);
    }
}

// twiddle v[brev4(tau)] *= W^tau for tau=1..15, W = exp(sgn*2pi*i*j/den)
__device__ __forceinline__ void stage_twiddle(float2 v[16], int j, float den, float sgn)
{
    float s, c;
    __sincosf(sgn * 6.283185307179586f * (float)j / den, &s, &c);
    float2 w1 = make_float2(c, s), wt = make_float2(1.f, 0.f);
    #pragma unroll
    for (int tau = 1; tau < 16; ++tau) {
        wt = cmul(wt, w1);
        v[brev4(tau)] = cmul(v[brev4(tau)], wt);
    }
}

// forward 4096-pt FFT in LDS (natural in at fpad(i)) -> brev12-scrambled
__device__ void fft4096_fwd(float2* d, int tid)
{
    float2 v[16];
    {   // stage 1: span 256
        const int j = tid;
        #pragma unroll
        for (int t = 0; t < 16; ++t) v[t] = d[fpad(j + (t << 8))];
        fft16_dif(v);
        stage_twiddle(v, j, 4096.0f, -1.0f);
        #pragma unroll
        for (int p = 0; p < 16; ++p) d[fpad(j + (p << 8))] = v[p];
    }
    __syncthreads();
    {   // stage 2: span 16 within 256-blocks
        const int base = ((tid >> 4) << 8) + (tid & 15);
        #pragma unroll
        for (int t = 0; t < 16; ++t) v[t] = d[fpad(base + (t << 4))];
        fft16_dif(v);
        stage_twiddle(v, tid & 15, 256.0f, -1.0f);
        #pragma unroll
        for (int p = 0; p < 16; ++p) d[fpad(base + (p << 4))] = v[p];
    }
    __syncthreads();
    {   // stage 3: contiguous 16
        const int base = tid << 4;
        #pragma unroll
        for (int t = 0; t < 16; ++t) v[t] = d[fpad(base + t)];
        fft16_dif(v);
        #pragma unroll
        for (int p = 0; p < 16; ++p) d[fpad(base + p)] = v[p];
    }
    __syncthreads();
}

// inverse: brev12-scrambled in -> natural out, scaled x4096
__device__ void fft4096_inv(float2* d, int tid)
{
    float2 v[16];
    {   // undo stage 3
        const int base = tid << 4;
        #pragma unroll
        for (int p = 0; p < 16; ++p) v[p] = d[fpad(base + p)];
        fft16_dit_inv(v);
        #pragma unroll
        for (int t = 0; t < 16; ++t) d[fpad(base + t)] = v[t];
    }
    __syncthreads();
    {   // undo stage 2
        const int base = ((tid >> 4) << 8) + (tid & 15);
        #pragma unroll
        for (int p = 0; p < 16; ++p) v[p] = d[fpad(base + (p << 4))];
        stage_twiddle(v, tid & 15, 256.0f, 1.0f);
        fft16_dit_inv(v);
        #pragma unroll
        for (int t = 0; t < 16; ++t) d[fpad(base + (t << 4))] = v[t];
    }
    __syncthreads();
    {   // undo stage 1
        const int j = tid;
        #pragma unroll
        for (int p = 0; p < 16; ++p) v[p] = d[fpad(j + (p << 8))];
        stage_twiddle(v, j, 4096.0f, 1.0f);
        fft16_dit_inv(v);
        #pragma unroll
        for (int t = 0; t < 16; ++t) d[fpad(j + (t << 8))] = v[t];
    }
    __syncthreads();
}

// ---------------------------------------------------------------------------
// F1: forward FFT of packed RPE kernel pairs -> Wspec (brev12 order)
// ---------------------------------------------------------------------------
__global__ __launch_bounds__(256) void fft_a_kernel(
    const float* __restrict__ a_t, float2* __restrict__ Wspec)
{
    __shared__ float2 data[FFT_LDS_SZ];
    const int tid = threadIdx.x;
    const int h = blockIdx.x / 96, dp = blockIdx.x % 96;

    const float* r0 = a_t + ((size_t)(h * HD + 2 * dp)) * M_FFT;
    const float* r1 = r0 + M_FFT;

    for (int j = tid; j < 4096; j += 256) data[fpad(j)] = make_float2(r0[j], r1[j]);
    __syncthreads();
    fft4096_fwd(data, tid);

    float2* outrow = Wspec + (size_t)blockIdx.x * 4096;
    for (int j = tid; j < 4096; j += 256) outrow[j] = data[fpad(j)];
}

// ---------------------------------------------------------------------------
// F2: FFT(v pair) * A-spectrum, inverse FFT, gate by u, write bf16 gated.
// ---------------------------------------------------------------------------
__global__ __launch_bounds__(256) void fft_conv_kernel(
    const float* __restrict__ v_t, const float2* __restrict__ Wspec,
    const float* __restrict__ ug, bf16* __restrict__ gated)
{
    __shared__ float2 data[FFT_LDS_SZ];
    const int tid = threadIdx.x;
    const int bx = blockIdx.x;
    const int b  = bx / 768;
    const int r  = bx % 768;
    const int h  = r / 96, dp = r % 96;

    const float* z0 = v_t + ((size_t)(b * D1 + h * HD + 2 * dp)) * N_SEQ;
    const float* z1 = z0 + N_SEQ;

    for (int s = tid; s < 2048; s += 256) data[fpad(s)] = make_float2(z0[s], z1[s]);
    for (int s = 2048 + tid; s < 4096; s += 256) data[fpad(s)] = make_float2(0.f, 0.f);
    __syncthreads();

    fft4096_fwd(data, tid);

    const float2* Wrow = Wspec + (size_t)r * 4096;
    for (int k = tid; k <= 2048; k += 256) {
        int km = (4096 - k) & 4095;
        int p1 = __brev((unsigned)k)  >> 20;
        int p2 = __brev((unsigned)km) >> 20;
        float2 Zk = data[fpad(p1)], Zm = data[fpad(p2)];
        float2 Wk = Wrow[p1], Wm = Wrow[p2];
        float2 V0 = make_float2(0.5f * (Zk.x + Zm.x), 0.5f * (Zk.y - Zm.y));
        float2 V1 = make_float2(0.5f * (Zk.y + Zm.y), 0.5f * (Zm.x - Zk.x));
        float2 A0 = make_float2(0.5f * (Wk.x + Wm.x), 0.5f * (Wk.y - Wm.y));
        float2 A1 = make_float2(0.5f * (Wk.y + Wm.y), 0.5f * (Wm.x - Wk.x));
        float2 P = make_float2(V0.x * A0.x - V0.y * A0.y, V0.x * A0.y + V0.y * A0.x);
        float2 Q = make_float2(V1.x * A1.x - V1.y * A1.y, V1.x * A1.y + V1.y * A1.x);
        data[fpad(p1)] = make_float2(P.x - Q.y, P.y + Q.x);
        if (k != 0 && k != 2048)
            data[fpad(p2)] = make_float2(P.x + Q.y, Q.x - P.y);
    }
    __syncthreads();

    fft4096_inv(data, tid);

    const float inv_m = 1.0f / 4096.0f;
    for (int t = tid; t < 2048; t += 256) {
        float2 y = data[fpad(t)];
        size_t base = ((size_t)(b * N_SEQ + t)) * D1 + h * HD + 2 * dp;
        gated[base]     = (bf16)(y.x * inv_m * ug[base]);
        gated[base + 1] = (bf16)(y.y * inv_m * ug[base + 1]);
    }
}

// ---------------------------------------------------------------------------
extern "C" void kernel_launch(void* const* d_in, const int* in_sizes, int n_in,
                              void* d_out, int out_size, void* d_ws, size_t ws_size,
                              hipStream_t stream)
{
    const float* x  = (const float*)d_in[0];
    const float* Wu = (const float*)d_in[1];
    const float* bu = (const float*)d_in[2];
    const float* Wv = (const float*)d_in[3];
    const float* bv = (const float*)d_in[4];
    const float* Wo = (const float*)d_in[5];
    const float* bo = (const float*)d_in[6];
    const float* Wp = (const float*)d_in[7];
    const float* bp = (const float*)d_in[8];
    const float* Wl = (const float*)d_in[9];
    const float* bl = (const float*)d_in[10];
    const float* Wr = (const float*)d_in[11];
    const float* br = (const float*)d_in[12];
    float* out = (float*)d_out;

    float* ws    = (float*)d_ws;
    float* u     = ws;                       // 8192*1536 fp32
    float* v_t   = u     + 12582912;         // [b][c][s] fp32
    float* a_t   = v_t   + 12582912;         // [c][j] fp32
    float* Wspec = a_t   + 6291456;          // 768 x 4096 float2
    float* h0    = Wspec + 6291456;          // 4096*512 fp32
    bf16*  bfws  = (bf16*)(h0 + 2097152);
    bf16*  x_bf  = bfws;
    bf16*  Wu_bf = x_bf  + 4194304;
    bf16*  Wv_bf = Wu_bf + 786432;
    bf16*  Wo_bf = Wv_bf + 786432;
    bf16*  Wl_bf = Wo_bf + 786432;
    bf16*  Wr_bf = Wl_bf + 786432;
    bf16*  g_bf  = Wr_bf + 786432;
    bf16*  gated = g_bf  + 2097152;

    dim3 blk(256);

    f2b_kernel<<<4194304 / 1024, blk, 0, stream>>>(x,  x_bf,  4194304);
    f2b_kernel<<<786432 / 1024, blk, 0, stream>>>(Wu, Wu_bf, 786432);
    f2b_kernel<<<786432 / 1024, blk, 0, stream>>>(Wv, Wv_bf, 786432);
    f2b_kernel<<<786432 / 1024, blk, 0, stream>>>(Wo, Wo_bf, 786432);
    f2b_kernel<<<786432 / 1024, blk, 0, stream>>>(Wl, Wl_bf, 786432);
    f2b_kernel<<<786432 / 1024, blk, 0, stream>>>(Wr, Wr_bf, 786432);

    gemm_bf16<MODE_SILU><<<dim3(12, 64), blk, 0, stream>>>(
        x_bf, Wu_bf, bu, u, 8192, D1, ED);
    gemm_bf16<MODE_SILU_VT><<<dim3(12, 64), blk, 0, stream>>>(
        x_bf, Wv_bf, bv, v_t, 8192, D1, ED);

    rpe_in_kernel<<<4096, blk, 0, stream>>>(Wp, bp, h0);
    srms_relu_kernel<<<4096, blk, 0, stream>>>(h0, g_bf);
    for (int i = 0; i < 3; ++i) {
        gemm_bf16<MODE_PLAIN><<<dim3(4, 32), blk, 0, stream>>>(
            g_bf, Wl_bf + (size_t)i * ED * ED, bl + (size_t)i * ED,
            h0, 4096, ED, ED);
        srms_relu_kernel<<<4096, blk, 0, stream>>>(h0, g_bf);
    }
    gemm_bf16<MODE_AT><<<dim3(12, 32), blk, 0, stream>>>(
        g_bf, Wr_bf, br, a_t, 4096, D1, ED);

    fft_a_kernel<<<768, blk, 0, stream>>>(a_t, (float2*)Wspec);
    fft_conv_kernel<<<3072, blk, 0, stream>>>(
        v_t, (const float2*)Wspec, u, gated);

    gemm_bf16<MODE_PLAIN><<<dim3(4, 64), blk, 0, stream>>>(
        gated, Wo_bf, bo, out, 8192, ED, D1);
}

// Round 4
// 431.687 us; speedup vs baseline: 2.7523x; 1.1350x over previous
//
#include <hip/hip_runtime.h>

#define N_SEQ 2048
#define M_FFT 4096
#define D1    1536
#define NH    8
#define HD    192
#define ED    512

typedef __bf16 bf16;
typedef __bf16 bf16x2 __attribute__((ext_vector_type(2)));
typedef __bf16 bf16x4 __attribute__((ext_vector_type(4)));
typedef __bf16 bf16x8 __attribute__((ext_vector_type(8)));
typedef float  floatx4 __attribute__((ext_vector_type(4)));

enum { MODE_PLAIN = 0, MODE_SILU = 1, MODE_SILU_VT = 2, MODE_AT = 3 };

__device__ __forceinline__ void gload16(const void* g, void* l) {
    __builtin_amdgcn_global_load_lds(
        (const __attribute__((address_space(1))) void*)g,
        (__attribute__((address_space(3))) void*)l, 16, 0, 0);
}

// ---------------------------------------------------------------------------
// bf16 MFMA GEMM (m97 structure): C = epilogue(A(MxK) @ Bw(NcxK)^T + bias)
// ---------------------------------------------------------------------------
template<int MODE, typename OutT>
__global__ __launch_bounds__(256) void gemm_bf16(
    const bf16* __restrict__ A, const bf16* __restrict__ Bw,
    const float* __restrict__ bias, OutT* __restrict__ C,
    int M, int Nc, int K)
{
    __shared__ __align__(16) bf16 As[128 * 32];
    __shared__ __align__(16) bf16 Bs[128 * 32];

    const int tid  = threadIdx.x;
    const int row0 = blockIdx.y * 128;
    const int col0 = blockIdx.x * 128;
    const int wid  = tid >> 6;
    const int lane = tid & 63;
    const int lm   = lane & 15;
    const int lk   = lane >> 4;
    const int wm   = wid >> 1;
    const int wn   = wid & 1;
    const int ldrow  = tid >> 2;
    const int ldcol8 = (tid & 3) * 8;

    floatx4 acc[4][4] = {};

    const bf16* Ag = A  + ((size_t)(row0 + ldrow)) * K + ldcol8;
    const bf16* Bg = Bw + ((size_t)(col0 + ldrow)) * K + ldcol8;
    bf16* AsW = As + (wid * 16) * 32;
    bf16* BsW = Bs + (wid * 16) * 32;

    for (int k0 = 0; k0 < K; k0 += 32) {
        gload16(Ag + k0, AsW);
        gload16(Ag + (size_t)64 * K + k0, AsW + 64 * 32);
        gload16(Bg + k0, BsW);
        gload16(Bg + (size_t)64 * K + k0, BsW + 64 * 32);
        __syncthreads();

        bf16x8 af[4], bfr[4];
        #pragma unroll
        for (int mi = 0; mi < 4; ++mi)
            af[mi] = *(const bf16x8*)&As[(wm * 64 + mi * 16 + lm) * 32 + lk * 8];
        #pragma unroll
        for (int nj = 0; nj < 4; ++nj)
            bfr[nj] = *(const bf16x8*)&Bs[(wn * 64 + nj * 16 + lm) * 32 + lk * 8];
        #pragma unroll
        for (int mi = 0; mi < 4; ++mi)
            #pragma unroll
            for (int nj = 0; nj < 4; ++nj)
                acc[mi][nj] = __builtin_amdgcn_mfma_f32_16x16x32_bf16(
                    af[mi], bfr[nj], acc[mi][nj], 0, 0, 0);
        __syncthreads();
    }

    float bcol[4];
    #pragma unroll
    for (int nj = 0; nj < 4; ++nj)
        bcol[nj] = bias[col0 + wn * 64 + nj * 16 + lm];

    #pragma unroll
    for (int mi = 0; mi < 4; ++mi) {
        #pragma unroll
        for (int nj = 0; nj < 4; ++nj) {
            const int col = col0 + wn * 64 + nj * 16 + lm;
            #pragma unroll
            for (int r = 0; r < 4; ++r) {
                const int row = row0 + wm * 64 + mi * 16 + lk * 4 + r;
                float val = acc[mi][nj][r] + bcol[nj];
                if (MODE == MODE_SILU || MODE == MODE_SILU_VT)
                    val = val / (1.0f + __expf(-val));
                if (MODE == MODE_SILU_VT) {
                    int b = row >> 11, s = row & 2047;
                    C[((size_t)(b * D1 + col)) * N_SEQ + s] = (OutT)val;
                } else if (MODE == MODE_AT) {
                    C[(size_t)col * M + row] = (OutT)val;
                } else {
                    C[(size_t)row * Nc + col] = (OutT)val;
                }
            }
        }
    }
}

// ---------------------------------------------------------------------------
__global__ __launch_bounds__(256) void f2b_kernel(
    const float* __restrict__ in, bf16* __restrict__ out, int n)
{
    int i = (blockIdx.x * 256 + threadIdx.x) * 4;
    if (i >= n) return;
    float4 f = *(const float4*)(in + i);
    union { bf16 h[4]; short4 s; } u4;
    u4.h[0] = (bf16)f.x; u4.h[1] = (bf16)f.y;
    u4.h[2] = (bf16)f.z; u4.h[3] = (bf16)f.w;
    *(short4*)(out + i) = u4.s;
}

__global__ __launch_bounds__(256) void rpe_in_kernel(
    const float* __restrict__ Wp, const float* __restrict__ bp,
    float* __restrict__ h0)
{
    int j = blockIdx.x;
    float idxv = (j < N_SEQ) ? (float)j
                             : (j == N_SEQ ? 0.0f : (float)(j - 2 * N_SEQ));
    for (int c = threadIdx.x; c < ED; c += 256)
        h0[(size_t)j * ED + c] = idxv * Wp[c] + bp[c];
}

__global__ __launch_bounds__(256) void srms_relu_kernel(
    const float* __restrict__ in, bf16* __restrict__ out)
{
    const int row = blockIdx.x;
    const int tid = threadIdx.x;
    const float* p = in + (size_t)row * ED;

    float ss = 0.0f;
    for (int i = tid; i < ED; i += 256) { float x = p[i]; ss += x * x; }
    #pragma unroll
    for (int off = 32; off > 0; off >>= 1) ss += __shfl_down(ss, off, 64);
    __shared__ float red[4];
    if ((tid & 63) == 0) red[tid >> 6] = ss;
    __syncthreads();
    float tot = red[0] + red[1] + red[2] + red[3];
    float scale = 1.0f / (sqrtf(tot) * 0.04419417382415922f + 1e-8f);
    for (int i = tid; i < ED; i += 256)
        out[(size_t)row * ED + i] = (bf16)fmaxf(p[i] * scale, 0.0f);
}

// ---------------------------------------------------------------------------
// Radix-16 FFT machinery (see round 2 notes). 4096 = 16^3.
// ---------------------------------------------------------------------------
#define FFT_LDS_SZ 4381

__device__ __forceinline__ int fpad(int i) { return i + (i >> 4) + 2 * (i >> 8); }

__device__ __forceinline__ float2 cmul(float2 a, float2 b) {
    return make_float2(a.x * b.x - a.y * b.y, a.x * b.y + a.y * b.x);
}
__device__ __forceinline__ float2 cadd(float2 a, float2 b) {
    return make_float2(a.x + b.x, a.y + b.y);
}
__device__ __forceinline__ float2 csub(float2 a, float2 b) {
    return make_float2(a.x - b.x, a.y - b.y);
}
__host__ __device__ constexpr int brev4(int t) {
    return ((t & 1) << 3) | ((t & 2) << 1) | ((t & 4) >> 1) | ((t & 8) >> 3);
}

template<bool FWD>
__device__ __forceinline__ void w16_tab(float2 w[8]) {
    const float sg = FWD ? -1.0f : 1.0f;
    const float C1 = 0.9238795325112867f, S1 = 0.3826834323650898f;
    const float C2 = 0.7071067811865476f;
    w[0] = make_float2( 1.f, 0.f);
    w[1] = make_float2( C1, sg * S1);
    w[2] = make_float2( C2, sg * C2);
    w[3] = make_float2( S1, sg * C1);
    w[4] = make_float2(0.f, sg * 1.f);
    w[5] = make_float2(-S1, sg * C1);
    w[6] = make_float2(-C2, sg * C2);
    w[7] = make_float2(-C1, sg * S1);
}

__device__ __forceinline__ void fft16_dif(float2 x[16]) {
    float2 w[8]; w16_tab<true>(w);
    #pragma unroll
    for (int k = 0; k < 8; ++k) {
        float2 u = x[k], t = x[k + 8];
        x[k] = cadd(u, t); x[k + 8] = cmul(csub(u, t), w[k]);
    }
    #pragma unroll
    for (int b = 0; b < 16; b += 8)
        #pragma unroll
        for (int k = 0; k < 4; ++k) {
            float2 u = x[b + k], t = x[b + k + 4];
            x[b + k] = cadd(u, t); x[b + k + 4] = cmul(csub(u, t), w[2 * k]);
        }
    #pragma unroll
    for (int b = 0; b < 16; b += 4)
        #pragma unroll
        for (int k = 0; k < 2; ++k) {
            float2 u = x[b + k], t = x[b + k + 2];
            x[b + k] = cadd(u, t); x[b + k + 2] = cmul(csub(u, t), w[4 * k]);
        }
    #pragma unroll
    for (int b = 0; b < 16; b += 2) {
        float2 u = x[b], t = x[b + 1];
        x[b] = cadd(u, t); x[b + 1] = csub(u, t);
    }
}

__device__ __forceinline__ void fft16_dit_inv(float2 x[16]) {
    float2 w[8]; w16_tab<false>(w);
    #pragma unroll
    for (int b = 0; b < 16; b += 2) {
        float2 u = x[b], t = x[b + 1];
        x[b] = cadd(u, t); x[b + 1] = csub(u, t);
    }
    #pragma unroll
    for (int b = 0; b < 16; b += 4)
        #pragma unroll
        for (int k = 0; k < 2; ++k) {
            float2 u = x[b + k], t = cmul(x[b + k + 2], w[4 * k]);
            x[b + k] = cadd(u, t); x[b + k + 2] = csub(u, t);
        }
    #pragma unroll
    for (int b = 0; b < 16; b += 8)
        #pragma unroll
        for (int k = 0; k < 4; ++k) {
            float2 u = x[b + k], t = cmul(x[b + k + 4], w[2 * k]);
            x[b + k] = cadd(u, t); x[b + k + 4] = csub(u, t);
        }
    #pragma unroll
    for (int k = 0; k < 8; ++k) {
        float2 u = x[k], t = cmul(x[k + 8], w[k]);
        x[k] = cadd(u, t); x[k + 8] = csub(u, t);
    }
}

__device__ __forceinline__ void stage_twiddle(float2 v[16], int j, float den, float sgn)
{
    float s, c;
    __sincosf(sgn * 6.283185307179586f * (float)j / den, &s, &c);
    float2 w1 = make_float2(c, s), wt = make_float2(1.f, 0.f);
    #pragma unroll
    for (int tau = 1; tau < 16; ++tau) {
        wt = cmul(wt, w1);
        v[brev4(tau)] = cmul(v[brev4(tau)], wt);
    }
}

__device__ void fft4096_fwd(float2* d, int tid)
{
    float2 v[16];
    {
        const int j = tid;
        #pragma unroll
        for (int t = 0; t < 16; ++t) v[t] = d[fpad(j + (t << 8))];
        fft16_dif(v);
        stage_twiddle(v, j, 4096.0f, -1.0f);
        #pragma unroll
        for (int p = 0; p < 16; ++p) d[fpad(j + (p << 8))] = v[p];
    }
    __syncthreads();
    {
        const int base = ((tid >> 4) << 8) + (tid & 15);
        #pragma unroll
        for (int t = 0; t < 16; ++t) v[t] = d[fpad(base + (t << 4))];
        fft16_dif(v);
        stage_twiddle(v, tid & 15, 256.0f, -1.0f);
        #pragma unroll
        for (int p = 0; p < 16; ++p) d[fpad(base + (p << 4))] = v[p];
    }
    __syncthreads();
    {
        const int base = tid << 4;
        #pragma unroll
        for (int t = 0; t < 16; ++t) v[t] = d[fpad(base + t)];
        fft16_dif(v);
        #pragma unroll
        for (int p = 0; p < 16; ++p) d[fpad(base + p)] = v[p];
    }
    __syncthreads();
}

__device__ void fft4096_inv(float2* d, int tid)
{
    float2 v[16];
    {
        const int base = tid << 4;
        #pragma unroll
        for (int p = 0; p < 16; ++p) v[p] = d[fpad(base + p)];
        fft16_dit_inv(v);
        #pragma unroll
        for (int t = 0; t < 16; ++t) d[fpad(base + t)] = v[t];
    }
    __syncthreads();
    {
        const int base = ((tid >> 4) << 8) + (tid & 15);
        #pragma unroll
        for (int p = 0; p < 16; ++p) v[p] = d[fpad(base + (p << 4))];
        stage_twiddle(v, tid & 15, 256.0f, 1.0f);
        fft16_dit_inv(v);
        #pragma unroll
        for (int t = 0; t < 16; ++t) d[fpad(base + (t << 4))] = v[t];
    }
    __syncthreads();
    {
        const int j = tid;
        #pragma unroll
        for (int p = 0; p < 16; ++p) v[p] = d[fpad(j + (p << 8))];
        stage_twiddle(v, j, 4096.0f, 1.0f);
        fft16_dit_inv(v);
        #pragma unroll
        for (int t = 0; t < 16; ++t) d[fpad(j + (t << 8))] = v[t];
    }
    __syncthreads();
}

// ---------------------------------------------------------------------------
__global__ __launch_bounds__(256) void fft_a_kernel(
    const float* __restrict__ a_t, float2* __restrict__ Wspec)
{
    __shared__ float2 data[FFT_LDS_SZ];
    const int tid = threadIdx.x;
    const int h = blockIdx.x / 96, dp = blockIdx.x % 96;

    const float* r0 = a_t + ((size_t)(h * HD + 2 * dp)) * M_FFT;
    const float* r1 = r0 + M_FFT;

    for (int j = tid; j < 4096; j += 256) data[fpad(j)] = make_float2(r0[j], r1[j]);
    __syncthreads();
    fft4096_fwd(data, tid);

    float2* outrow = Wspec + (size_t)blockIdx.x * 4096;
    for (int j = tid; j < 4096; j += 256) outrow[j] = data[fpad(j)];
}

// ---------------------------------------------------------------------------
// F2: FFT(v pair) * A-spectrum, inverse FFT, gate by u_t (bf16, [b][c][s]),
// write gated_t (bf16, [b][c][s]) — all global accesses coalesced.
// ---------------------------------------------------------------------------
__global__ __launch_bounds__(256) void fft_conv_kernel(
    const float* __restrict__ v_t, const float2* __restrict__ Wspec,
    const bf16* __restrict__ u_t, bf16* __restrict__ gated_t)
{
    __shared__ float2 data[FFT_LDS_SZ];
    const int tid = threadIdx.x;
    const int bx = blockIdx.x;
    const int b  = bx / 768;
    const int r  = bx % 768;
    const int h  = r / 96, dp = r % 96;
    const int ch = h * HD + 2 * dp;

    const float* z0 = v_t + ((size_t)(b * D1 + ch)) * N_SEQ;
    const float* z1 = z0 + N_SEQ;

    for (int s = tid * 2; s < 2048; s += 512) {
        float2 a0 = *(const float2*)(z0 + s);
        float2 a1 = *(const float2*)(z1 + s);
        data[fpad(s)]     = make_float2(a0.x, a1.x);
        data[fpad(s + 1)] = make_float2(a0.y, a1.y);
    }
    for (int s = 2048 + tid * 2; s < 4096; s += 512) {
        data[fpad(s)]     = make_float2(0.f, 0.f);
        data[fpad(s + 1)] = make_float2(0.f, 0.f);
    }
    __syncthreads();

    fft4096_fwd(data, tid);

    const float2* Wrow = Wspec + (size_t)r * 4096;
    for (int k = tid; k <= 2048; k += 256) {
        int km = (4096 - k) & 4095;
        int p1 = __brev((unsigned)k)  >> 20;
        int p2 = __brev((unsigned)km) >> 20;
        float2 Zk = data[fpad(p1)], Zm = data[fpad(p2)];
        float2 Wk = Wrow[p1], Wm = Wrow[p2];
        float2 V0 = make_float2(0.5f * (Zk.x + Zm.x), 0.5f * (Zk.y - Zm.y));
        float2 V1 = make_float2(0.5f * (Zk.y + Zm.y), 0.5f * (Zm.x - Zk.x));
        float2 A0 = make_float2(0.5f * (Wk.x + Wm.x), 0.5f * (Wk.y - Wm.y));
        float2 A1 = make_float2(0.5f * (Wk.y + Wm.y), 0.5f * (Wm.x - Wk.x));
        float2 P = make_float2(V0.x * A0.x - V0.y * A0.y, V0.x * A0.y + V0.y * A0.x);
        float2 Q = make_float2(V1.x * A1.x - V1.y * A1.y, V1.x * A1.y + V1.y * A1.x);
        data[fpad(p1)] = make_float2(P.x - Q.y, P.y + Q.x);
        if (k != 0 && k != 2048)
            data[fpad(p2)] = make_float2(P.x + Q.y, Q.x - P.y);
    }
    __syncthreads();

    fft4096_inv(data, tid);

    const float inv_m = 1.0f / 4096.0f;
    const bf16* u0 = u_t + ((size_t)(b * D1 + ch)) * N_SEQ;
    const bf16* u1 = u0 + N_SEQ;
    bf16* g0 = gated_t + ((size_t)(b * D1 + ch)) * N_SEQ;
    bf16* g1 = g0 + N_SEQ;
    for (int t = tid * 2; t < 2048; t += 512) {
        float2 ya = data[fpad(t)], yb = data[fpad(t + 1)];
        bf16x2 ua = *(const bf16x2*)(u0 + t);
        bf16x2 ub = *(const bf16x2*)(u1 + t);
        bf16x2 oa, ob;
        oa[0] = (bf16)(ya.x * inv_m * (float)ua[0]);
        oa[1] = (bf16)(yb.x * inv_m * (float)ua[1]);
        ob[0] = (bf16)(ya.y * inv_m * (float)ub[0]);
        ob[1] = (bf16)(yb.y * inv_m * (float)ub[1]);
        *(bf16x2*)(g0 + t) = oa;
        *(bf16x2*)(g1 + t) = ob;
    }
}

// ---------------------------------------------------------------------------
// gated_t [b][c][s] bf16 -> gated [b*2048+s][c] bf16 via 64x64 LDS tile
// ---------------------------------------------------------------------------
__global__ __launch_bounds__(256) void transpose_cs_kernel(
    const bf16* __restrict__ in, bf16* __restrict__ outp)
{
    __shared__ bf16 tile[64 * 68];
    const int c0 = blockIdx.x * 64;
    const int m0 = blockIdx.y * 64;
    const int b  = m0 >> 11;
    const int s0 = m0 & 2047;
    const int tid = threadIdx.x;
    const int cl = tid >> 4;
    const int sc = (tid & 15) * 4;
    #pragma unroll
    for (int p = 0; p < 4; ++p) {
        int c = p * 16 + cl;
        bf16x4 v = *(const bf16x4*)&in[((size_t)(b * D1 + c0 + c)) * N_SEQ + s0 + sc];
        *(bf16x4*)&tile[c * 68 + sc] = v;
    }
    __syncthreads();
    const int sl = tid >> 4;
    const int cc = (tid & 15) * 4;
    #pragma unroll
    for (int p = 0; p < 4; ++p) {
        int s = p * 16 + sl;
        bf16x4 o;
        #pragma unroll
        for (int j = 0; j < 4; ++j) o[j] = tile[(cc + j) * 68 + s];
        *(bf16x4*)&outp[((size_t)(m0 + s)) * D1 + c0 + cc] = o;
    }
}

// ---------------------------------------------------------------------------
extern "C" void kernel_launch(void* const* d_in, const int* in_sizes, int n_in,
                              void* d_out, int out_size, void* d_ws, size_t ws_size,
                              hipStream_t stream)
{
    const float* x  = (const float*)d_in[0];
    const float* Wu = (const float*)d_in[1];
    const float* bu = (const float*)d_in[2];
    const float* Wv = (const float*)d_in[3];
    const float* bv = (const float*)d_in[4];
    const float* Wo = (const float*)d_in[5];
    const float* bo = (const float*)d_in[6];
    const float* Wp = (const float*)d_in[7];
    const float* bp = (const float*)d_in[8];
    const float* Wl = (const float*)d_in[9];
    const float* bl = (const float*)d_in[10];
    const float* Wr = (const float*)d_in[11];
    const float* br = (const float*)d_in[12];
    float* out = (float*)d_out;

    float* ws      = (float*)d_ws;
    float* v_t     = ws;                       // 8192*1536 fp32 [b][c][s]
    float* a_t     = v_t   + 12582912;         // 1536*4096 fp32
    float* Wspec   = a_t   + 6291456;          // 768 x 4096 float2
    float* h0      = Wspec + 6291456;          // 4096*512 fp32
    bf16*  bfws    = (bf16*)(h0 + 2097152);
    bf16*  x_bf    = bfws;                     // 8192*512
    bf16*  Wu_bf   = x_bf    + 4194304;
    bf16*  Wv_bf   = Wu_bf   + 786432;
    bf16*  Wo_bf   = Wv_bf   + 786432;
    bf16*  Wl_bf   = Wo_bf   + 786432;
    bf16*  Wr_bf   = Wl_bf   + 786432;
    bf16*  g_bf    = Wr_bf   + 786432;         // 4096*512
    bf16*  u_t     = g_bf    + 2097152;        // 8192*1536 bf16 [b][c][s]
    bf16*  gated_t = u_t     + 12582912;       // 8192*1536 bf16 [b][c][s]
    bf16*  gated   = gated_t + 12582912;       // 8192*1536 bf16 [m][c]

    dim3 blk(256);

    f2b_kernel<<<4194304 / 1024, blk, 0, stream>>>(x,  x_bf,  4194304);
    f2b_kernel<<<786432 / 1024, blk, 0, stream>>>(Wu, Wu_bf, 786432);
    f2b_kernel<<<786432 / 1024, blk, 0, stream>>>(Wv, Wv_bf, 786432);
    f2b_kernel<<<786432 / 1024, blk, 0, stream>>>(Wo, Wo_bf, 786432);
    f2b_kernel<<<786432 / 1024, blk, 0, stream>>>(Wl, Wl_bf, 786432);
    f2b_kernel<<<786432 / 1024, blk, 0, stream>>>(Wr, Wr_bf, 786432);

    // u = silu(x@Wu^T+bu) -> u_t bf16 [b][c][s]; v likewise fp32
    gemm_bf16<MODE_SILU_VT, bf16><<<dim3(12, 64), blk, 0, stream>>>(
        x_bf, Wu_bf, bu, u_t, 8192, D1, ED);
    gemm_bf16<MODE_SILU_VT, float><<<dim3(12, 64), blk, 0, stream>>>(
        x_bf, Wv_bf, bv, v_t, 8192, D1, ED);

    rpe_in_kernel<<<4096, blk, 0, stream>>>(Wp, bp, h0);
    srms_relu_kernel<<<4096, blk, 0, stream>>>(h0, g_bf);
    for (int i = 0; i < 3; ++i) {
        gemm_bf16<MODE_PLAIN, float><<<dim3(4, 32), blk, 0, stream>>>(
            g_bf, Wl_bf + (size_t)i * ED * ED, bl + (size_t)i * ED,
            h0, 4096, ED, ED);
        srms_relu_kernel<<<4096, blk, 0, stream>>>(h0, g_bf);
    }
    gemm_bf16<MODE_AT, float><<<dim3(12, 32), blk, 0, stream>>>(
        g_bf, Wr_bf, br, a_t, 4096, D1, ED);

    fft_a_kernel<<<768, blk, 0, stream>>>(a_t, (float2*)Wspec);
    fft_conv_kernel<<<3072, blk, 0, stream>>>(
        v_t, (const float2*)Wspec, u_t, gated_t);

    transpose_cs_kernel<<<dim3(24, 128), blk, 0, stream>>>(gated_t, gated);

    gemm_bf16<MODE_PLAIN, float><<<dim3(4, 64), blk, 0, stream>>>(
        gated, Wo_bf, bo, out, 8192, ED, D1);
}

// Round 5
// 380.713 us; speedup vs baseline: 3.1208x; 1.1339x over previous
//
#include <hip/hip_runtime.h>

#define N_SEQ 2048
#define M_FFT 4096
#define D1    1536
#define NH    8
#define HD    192
#define ED    512

typedef __bf16 bf16;
typedef __bf16 bf16x2 __attribute__((ext_vector_type(2)));
typedef __bf16 bf16x4 __attribute__((ext_vector_type(4)));
typedef __bf16 bf16x8 __attribute__((ext_vector_type(8)));
typedef float  floatx4 __attribute__((ext_vector_type(4)));

enum { MODE_PLAIN = 0, MODE_SILU_VT = 2, MODE_AT = 3 };

__device__ __forceinline__ void gload16(const void* g, void* l) {
    __builtin_amdgcn_global_load_lds(
        (const __attribute__((address_space(1))) void*)g,
        (__attribute__((address_space(3))) void*)l, 16, 0, 0);
}

// ---------------------------------------------------------------------------
// bf16 MFMA GEMM (m97 structure): C = epilogue(A(MxK) @ Bw(NcxK)^T + bias)
// ---------------------------------------------------------------------------
template<int MODE, typename OutT>
__global__ __launch_bounds__(256) void gemm_bf16(
    const bf16* __restrict__ A, const bf16* __restrict__ Bw,
    const float* __restrict__ bias, OutT* __restrict__ C,
    int M, int Nc, int K)
{
    __shared__ __align__(16) bf16 As[128 * 32];
    __shared__ __align__(16) bf16 Bs[128 * 32];

    const int tid  = threadIdx.x;
    const int row0 = blockIdx.y * 128;
    const int col0 = blockIdx.x * 128;
    const int wid  = tid >> 6;
    const int lane = tid & 63;
    const int lm   = lane & 15;
    const int lk   = lane >> 4;
    const int wm   = wid >> 1;
    const int wn   = wid & 1;
    const int ldrow  = tid >> 2;
    const int ldcol8 = (tid & 3) * 8;

    floatx4 acc[4][4] = {};

    const bf16* Ag = A  + ((size_t)(row0 + ldrow)) * K + ldcol8;
    const bf16* Bg = Bw + ((size_t)(col0 + ldrow)) * K + ldcol8;
    bf16* AsW = As + (wid * 16) * 32;
    bf16* BsW = Bs + (wid * 16) * 32;

    for (int k0 = 0; k0 < K; k0 += 32) {
        gload16(Ag + k0, AsW);
        gload16(Ag + (size_t)64 * K + k0, AsW + 64 * 32);
        gload16(Bg + k0, BsW);
        gload16(Bg + (size_t)64 * K + k0, BsW + 64 * 32);
        __syncthreads();

        bf16x8 af[4], bfr[4];
        #pragma unroll
        for (int mi = 0; mi < 4; ++mi)
            af[mi] = *(const bf16x8*)&As[(wm * 64 + mi * 16 + lm) * 32 + lk * 8];
        #pragma unroll
        for (int nj = 0; nj < 4; ++nj)
            bfr[nj] = *(const bf16x8*)&Bs[(wn * 64 + nj * 16 + lm) * 32 + lk * 8];
        #pragma unroll
        for (int mi = 0; mi < 4; ++mi)
            #pragma unroll
            for (int nj = 0; nj < 4; ++nj)
                acc[mi][nj] = __builtin_amdgcn_mfma_f32_16x16x32_bf16(
                    af[mi], bfr[nj], acc[mi][nj], 0, 0, 0);
        __syncthreads();
    }

    float bcol[4];
    #pragma unroll
    for (int nj = 0; nj < 4; ++nj)
        bcol[nj] = bias[col0 + wn * 64 + nj * 16 + lm];

    #pragma unroll
    for (int mi = 0; mi < 4; ++mi) {
        const int rbase = row0 + wm * 64 + mi * 16 + lk * 4;
        #pragma unroll
        for (int nj = 0; nj < 4; ++nj) {
            const int col = col0 + wn * 64 + nj * 16 + lm;
            float vals[4];
            #pragma unroll
            for (int r = 0; r < 4; ++r) {
                float val = acc[mi][nj][r] + bcol[nj];
                if (MODE == MODE_SILU_VT)
                    val = val / (1.0f + __expf(-val));
                vals[r] = val;
            }
            if (MODE == MODE_SILU_VT) {
                // v_t / u_t [b][c][s], s contiguous in r
                int b = rbase >> 11, s = rbase & 2047;
                bf16x4 o;
                #pragma unroll
                for (int r = 0; r < 4; ++r) o[r] = (bf16)vals[r];
                *(bf16x4*)&((bf16*)C)[((size_t)(b * D1 + col)) * N_SEQ + s] = o;
            } else if (MODE == MODE_AT) {
                float4 o = make_float4(vals[0], vals[1], vals[2], vals[3]);
                *(float4*)&((float*)C)[(size_t)col * M + rbase] = o;
            } else {
                #pragma unroll
                for (int r = 0; r < 4; ++r)
                    C[(size_t)(rbase + r) * Nc + col] = (OutT)vals[r];
            }
        }
    }
}

// ---------------------------------------------------------------------------
__global__ __launch_bounds__(256) void f2b_kernel(
    const float* __restrict__ in, bf16* __restrict__ out, int n)
{
    int i = (blockIdx.x * 256 + threadIdx.x) * 4;
    if (i >= n) return;
    float4 f = *(const float4*)(in + i);
    union { bf16 h[4]; short4 s; } u4;
    u4.h[0] = (bf16)f.x; u4.h[1] = (bf16)f.y;
    u4.h[2] = (bf16)f.z; u4.h[3] = (bf16)f.w;
    *(short4*)(out + i) = u4.s;
}

// 5 equal 786432-element weight blobs -> contiguous bf16 region
__global__ __launch_bounds__(256) void f2b5_kernel(
    const float* __restrict__ s0, const float* __restrict__ s1,
    const float* __restrict__ s2, const float* __restrict__ s3,
    const float* __restrict__ s4, bf16* __restrict__ dst)
{
    const int seg = blockIdx.y;
    const float* src = seg == 0 ? s0 : seg == 1 ? s1 : seg == 2 ? s2
                     : seg == 3 ? s3 : s4;
    int i = (blockIdx.x * 256 + threadIdx.x) * 4;
    float4 f = *(const float4*)(src + i);
    union { bf16 h[4]; short4 s; } u4;
    u4.h[0] = (bf16)f.x; u4.h[1] = (bf16)f.y;
    u4.h[2] = (bf16)f.z; u4.h[3] = (bf16)f.w;
    *(short4*)(dst + (size_t)seg * 786432 + i) = u4.s;
}

// ---------------------------------------------------------------------------
// fused RPE input layer + srms+relu -> g_bf
// ---------------------------------------------------------------------------
__global__ __launch_bounds__(256) void rpe_in_srms_kernel(
    const float* __restrict__ Wp, const float* __restrict__ bp,
    bf16* __restrict__ g)
{
    const int j = blockIdx.x;
    const int tid = threadIdx.x;
    float idxv = (j < N_SEQ) ? (float)j
                             : (j == N_SEQ ? 0.0f : (float)(j - 2 * N_SEQ));
    float h1 = idxv * Wp[tid] + bp[tid];
    float h2 = idxv * Wp[tid + 256] + bp[tid + 256];
    float ss = h1 * h1 + h2 * h2;
    #pragma unroll
    for (int off = 32; off > 0; off >>= 1) ss += __shfl_down(ss, off, 64);
    __shared__ float red[4];
    if ((tid & 63) == 0) red[tid >> 6] = ss;
    __syncthreads();
    float tot = red[0] + red[1] + red[2] + red[3];
    float scale = 1.0f / (sqrtf(tot) * 0.04419417382415922f + 1e-8f);
    g[(size_t)j * ED + tid]       = (bf16)fmaxf(h1 * scale, 0.0f);
    g[(size_t)j * ED + tid + 256] = (bf16)fmaxf(h2 * scale, 0.0f);
}

__global__ __launch_bounds__(256) void srms_relu_kernel(
    const float* __restrict__ in, bf16* __restrict__ out)
{
    const int row = blockIdx.x;
    const int tid = threadIdx.x;
    const float* p = in + (size_t)row * ED;

    float ss = 0.0f;
    for (int i = tid; i < ED; i += 256) { float x = p[i]; ss += x * x; }
    #pragma unroll
    for (int off = 32; off > 0; off >>= 1) ss += __shfl_down(ss, off, 64);
    __shared__ float red[4];
    if ((tid & 63) == 0) red[tid >> 6] = ss;
    __syncthreads();
    float tot = red[0] + red[1] + red[2] + red[3];
    float scale = 1.0f / (sqrtf(tot) * 0.04419417382415922f + 1e-8f);
    for (int i = tid; i < ED; i += 256)
        out[(size_t)row * ED + i] = (bf16)fmaxf(p[i] * scale, 0.0f);
}

// ---------------------------------------------------------------------------
// Radix-16 FFT machinery. 4096 = 16^3, 256 threads x 16 complex in registers.
// ---------------------------------------------------------------------------
#define FFT_LDS_SZ 4381

__device__ __forceinline__ int fpad(int i) { return i + (i >> 4) + 2 * (i >> 8); }

__device__ __forceinline__ float2 cmul(float2 a, float2 b) {
    return make_float2(a.x * b.x - a.y * b.y, a.x * b.y + a.y * b.x);
}
__device__ __forceinline__ float2 cadd(float2 a, float2 b) {
    return make_float2(a.x + b.x, a.y + b.y);
}
__device__ __forceinline__ float2 csub(float2 a, float2 b) {
    return make_float2(a.x - b.x, a.y - b.y);
}
__host__ __device__ constexpr int brev4(int t) {
    return ((t & 1) << 3) | ((t & 2) << 1) | ((t & 4) >> 1) | ((t & 8) >> 3);
}

template<bool FWD>
__device__ __forceinline__ void w16_tab(float2 w[8]) {
    const float sg = FWD ? -1.0f : 1.0f;
    const float C1 = 0.9238795325112867f, S1 = 0.3826834323650898f;
    const float C2 = 0.7071067811865476f;
    w[0] = make_float2( 1.f, 0.f);
    w[1] = make_float2( C1, sg * S1);
    w[2] = make_float2( C2, sg * C2);
    w[3] = make_float2( S1, sg * C1);
    w[4] = make_float2(0.f, sg * 1.f);
    w[5] = make_float2(-S1, sg * C1);
    w[6] = make_float2(-C2, sg * C2);
    w[7] = make_float2(-C1, sg * S1);
}

// levels 2..4 of the 16-pt DIF (shared by full and half-zero variants)
__device__ __forceinline__ void fft16_dif_tail(float2 x[16], const float2 w[8]) {
    #pragma unroll
    for (int b = 0; b < 16; b += 8)
        #pragma unroll
        for (int k = 0; k < 4; ++k) {
            float2 u = x[b + k], t = x[b + k + 4];
            x[b + k] = cadd(u, t); x[b + k + 4] = cmul(csub(u, t), w[2 * k]);
        }
    #pragma unroll
    for (int b = 0; b < 16; b += 4)
        #pragma unroll
        for (int k = 0; k < 2; ++k) {
            float2 u = x[b + k], t = x[b + k + 2];
            x[b + k] = cadd(u, t); x[b + k + 2] = cmul(csub(u, t), w[4 * k]);
        }
    #pragma unroll
    for (int b = 0; b < 16; b += 2) {
        float2 u = x[b], t = x[b + 1];
        x[b] = cadd(u, t); x[b + 1] = csub(u, t);
    }
}

__device__ __forceinline__ void fft16_dif(float2 x[16]) {
    float2 w[8]; w16_tab<true>(w);
    #pragma unroll
    for (int k = 0; k < 8; ++k) {
        float2 u = x[k], t = x[k + 8];
        x[k] = cadd(u, t); x[k + 8] = cmul(csub(u, t), w[k]);
    }
    fft16_dif_tail(x, w);
}

// upper half of inputs (x[8..15]) is zero and not initialized
__device__ __forceinline__ void fft16_dif_halfzero(float2 x[16]) {
    float2 w[8]; w16_tab<true>(w);
    x[8] = x[0];
    #pragma unroll
    for (int k = 1; k < 8; ++k) x[k + 8] = cmul(x[k], w[k]);
    fft16_dif_tail(x, w);
}

template<bool HALF_OUT>
__device__ __forceinline__ void fft16_dit_inv(float2 x[16]) {
    float2 w[8]; w16_tab<false>(w);
    #pragma unroll
    for (int b = 0; b < 16; b += 2) {
        float2 u = x[b], t = x[b + 1];
        x[b] = cadd(u, t); x[b + 1] = csub(u, t);
    }
    #pragma unroll
    for (int b = 0; b < 16; b += 4)
        #pragma unroll
        for (int k = 0; k < 2; ++k) {
            float2 u = x[b + k], t = cmul(x[b + k + 2], w[4 * k]);
            x[b + k] = cadd(u, t); x[b + k + 2] = csub(u, t);
        }
    #pragma unroll
    for (int b = 0; b < 16; b += 8)
        #pragma unroll
        for (int k = 0; k < 4; ++k) {
            float2 u = x[b + k], t = cmul(x[b + k + 4], w[2 * k]);
            x[b + k] = cadd(u, t); x[b + k + 4] = csub(u, t);
        }
    #pragma unroll
    for (int k = 0; k < 8; ++k) {
        float2 u = x[k], t = cmul(x[k + 8], w[k]);
        x[k] = cadd(u, t);
        if (!HALF_OUT) x[k + 8] = csub(u, t);
    }
}

__device__ __forceinline__ void stage_twiddle(float2 v[16], int j, float den, float sgn)
{
    float s, c;
    __sincosf(sgn * 6.283185307179586f * (float)j / den, &s, &c);
    float2 w1 = make_float2(c, s), wt = make_float2(1.f, 0.f);
    #pragma unroll
    for (int tau = 1; tau < 16; ++tau) {
        wt = cmul(wt, w1);
        v[brev4(tau)] = cmul(v[brev4(tau)], wt);
    }
}

// forward 4096-pt FFT; if HALF_ZERO, positions >= 2048 are implicitly zero
// (and never read). natural in at fpad(i) -> brev12-scrambled out.
template<bool HALF_ZERO>
__device__ void fft4096_fwd(float2* d, int tid)
{
    float2 v[16];
    {   // stage 1: span 256
        const int j = tid;
        if (HALF_ZERO) {
            #pragma unroll
            for (int t = 0; t < 8; ++t) v[t] = d[fpad(j + (t << 8))];
            fft16_dif_halfzero(v);
        } else {
            #pragma unroll
            for (int t = 0; t < 16; ++t) v[t] = d[fpad(j + (t << 8))];
            fft16_dif(v);
        }
        stage_twiddle(v, j, 4096.0f, -1.0f);
        #pragma unroll
        for (int p = 0; p < 16; ++p) d[fpad(j + (p << 8))] = v[p];
    }
    __syncthreads();
    {   // stage 2: span 16
        const int base = ((tid >> 4) << 8) + (tid & 15);
        #pragma unroll
        for (int t = 0; t < 16; ++t) v[t] = d[fpad(base + (t << 4))];
        fft16_dif(v);
        stage_twiddle(v, tid & 15, 256.0f, -1.0f);
        #pragma unroll
        for (int p = 0; p < 16; ++p) d[fpad(base + (p << 4))] = v[p];
    }
    __syncthreads();
    {   // stage 3: contiguous 16
        const int base = tid << 4;
        #pragma unroll
        for (int t = 0; t < 16; ++t) v[t] = d[fpad(base + t)];
        fft16_dif(v);
        #pragma unroll
        for (int p = 0; p < 16; ++p) d[fpad(base + p)] = v[p];
    }
    __syncthreads();
}

// inverse: brev12-scrambled in -> natural out (x4096 scale); if HALF_OUT,
// only positions < 2048 are produced.
template<bool HALF_OUT>
__device__ void fft4096_inv(float2* d, int tid)
{
    float2 v[16];
    {
        const int base = tid << 4;
        #pragma unroll
        for (int p = 0; p < 16; ++p) v[p] = d[fpad(base + p)];
        fft16_dit_inv<false>(v);
        #pragma unroll
        for (int t = 0; t < 16; ++t) d[fpad(base + t)] = v[t];
    }
    __syncthreads();
    {
        const int base = ((tid >> 4) << 8) + (tid & 15);
        #pragma unroll
        for (int p = 0; p < 16; ++p) v[p] = d[fpad(base + (p << 4))];
        stage_twiddle(v, tid & 15, 256.0f, 1.0f);
        fft16_dit_inv<false>(v);
        #pragma unroll
        for (int t = 0; t < 16; ++t) d[fpad(base + (t << 4))] = v[t];
    }
    __syncthreads();
    {
        const int j = tid;
        #pragma unroll
        for (int p = 0; p < 16; ++p) v[p] = d[fpad(j + (p << 8))];
        stage_twiddle(v, j, 4096.0f, 1.0f);
        fft16_dit_inv<HALF_OUT>(v);
        #pragma unroll
        for (int t = 0; t < (HALF_OUT ? 8 : 16); ++t) d[fpad(j + (t << 8))] = v[t];
    }
    __syncthreads();
}

// ---------------------------------------------------------------------------
__global__ __launch_bounds__(256) void fft_a_kernel(
    const float* __restrict__ a_t, float2* __restrict__ Wspec)
{
    __shared__ float2 data[FFT_LDS_SZ];
    const int tid = threadIdx.x;
    const int h = blockIdx.x / 96, dp = blockIdx.x % 96;

    const float* r0 = a_t + ((size_t)(h * HD + 2 * dp)) * M_FFT;
    const float* r1 = r0 + M_FFT;

    for (int j = tid; j < 4096; j += 256) data[fpad(j)] = make_float2(r0[j], r1[j]);
    __syncthreads();
    fft4096_fwd<false>(data, tid);

    float2* outrow = Wspec + (size_t)blockIdx.x * 4096;
    for (int j = tid; j < 4096; j += 256) outrow[j] = data[fpad(j)];
}

// ---------------------------------------------------------------------------
// F2: FFT(v pair bf16) * A-spectrum, inverse FFT, gate by u_t bf16, all
// global accesses coalesced 16 B.
// ---------------------------------------------------------------------------
__global__ __launch_bounds__(256) void fft_conv_kernel(
    const bf16* __restrict__ v_t, const float2* __restrict__ Wspec,
    const bf16* __restrict__ u_t, bf16* __restrict__ gated_t)
{
    __shared__ float2 data[FFT_LDS_SZ];
    const int tid = threadIdx.x;
    const int bx = blockIdx.x;
    const int b  = bx / 768;
    const int r  = bx % 768;
    const int h  = r / 96, dp = r % 96;
    const int ch = h * HD + 2 * dp;

    const bf16* z0 = v_t + ((size_t)(b * D1 + ch)) * N_SEQ;
    const bf16* z1 = z0 + N_SEQ;

    {
        const int s = tid * 8;
        bf16x8 a0 = *(const bf16x8*)(z0 + s);
        bf16x8 a1 = *(const bf16x8*)(z1 + s);
        #pragma unroll
        for (int i = 0; i < 8; ++i)
            data[fpad(s + i)] = make_float2((float)a0[i], (float)a1[i]);
    }
    __syncthreads();

    fft4096_fwd<true>(data, tid);

    const float2* Wrow = Wspec + (size_t)r * 4096;
    for (int k = tid; k <= 2048; k += 256) {
        int km = (4096 - k) & 4095;
        int p1 = __brev((unsigned)k)  >> 20;
        int p2 = __brev((unsigned)km) >> 20;
        float2 Zk = data[fpad(p1)], Zm = data[fpad(p2)];
        float2 Wk = Wrow[p1], Wm = Wrow[p2];
        float2 V0 = make_float2(0.5f * (Zk.x + Zm.x), 0.5f * (Zk.y - Zm.y));
        float2 V1 = make_float2(0.5f * (Zk.y + Zm.y), 0.5f * (Zm.x - Zk.x));
        float2 A0 = make_float2(0.5f * (Wk.x + Wm.x), 0.5f * (Wk.y - Wm.y));
        float2 A1 = make_float2(0.5f * (Wk.y + Wm.y), 0.5f * (Wm.x - Wk.x));
        float2 P = make_float2(V0.x * A0.x - V0.y * A0.y, V0.x * A0.y + V0.y * A0.x);
        float2 Q = make_float2(V1.x * A1.x - V1.y * A1.y, V1.x * A1.y + V1.y * A1.x);
        data[fpad(p1)] = make_float2(P.x - Q.y, P.y + Q.x);
        if (k != 0 && k != 2048)
            data[fpad(p2)] = make_float2(P.x + Q.y, Q.x - P.y);
    }
    __syncthreads();

    fft4096_inv<true>(data, tid);

    const float inv_m = 1.0f / 4096.0f;
    const bf16* u0 = u_t + ((size_t)(b * D1 + ch)) * N_SEQ;
    const bf16* u1 = u0 + N_SEQ;
    bf16* g0 = gated_t + ((size_t)(b * D1 + ch)) * N_SEQ;
    bf16* g1 = g0 + N_SEQ;
    {
        const int t = tid * 8;
        bf16x8 ua = *(const bf16x8*)(u0 + t);
        bf16x8 ub = *(const bf16x8*)(u1 + t);
        bf16x8 oa, ob;
        #pragma unroll
        for (int i = 0; i < 8; ++i) {
            float2 y = data[fpad(t + i)];
            oa[i] = (bf16)(y.x * inv_m * (float)ua[i]);
            ob[i] = (bf16)(y.y * inv_m * (float)ub[i]);
        }
        *(bf16x8*)(g0 + t) = oa;
        *(bf16x8*)(g1 + t) = ob;
    }
}

// ---------------------------------------------------------------------------
// gated_t [b][c][s] bf16 -> gated [b*2048+s][c] bf16 via 64x64 LDS tile
// ---------------------------------------------------------------------------
__global__ __launch_bounds__(256) void transpose_cs_kernel(
    const bf16* __restrict__ in, bf16* __restrict__ outp)
{
    __shared__ bf16 tile[64 * 68];
    const int c0 = blockIdx.x * 64;
    const int m0 = blockIdx.y * 64;
    const int b  = m0 >> 11;
    const int s0 = m0 & 2047;
    const int tid = threadIdx.x;
    const int cl = tid >> 4;
    const int sc = (tid & 15) * 4;
    #pragma unroll
    for (int p = 0; p < 4; ++p) {
        int c = p * 16 + cl;
        bf16x4 v = *(const bf16x4*)&in[((size_t)(b * D1 + c0 + c)) * N_SEQ + s0 + sc];
        *(bf16x4*)&tile[c * 68 + sc] = v;
    }
    __syncthreads();
    const int sl = tid >> 4;
    const int cc = (tid & 15) * 4;
    #pragma unroll
    for (int p = 0; p < 4; ++p) {
        int s = p * 16 + sl;
        bf16x4 o;
        #pragma unroll
        for (int j = 0; j < 4; ++j) o[j] = tile[(cc + j) * 68 + s];
        *(bf16x4*)&outp[((size_t)(m0 + s)) * D1 + c0 + cc] = o;
    }
}

// ---------------------------------------------------------------------------
extern "C" void kernel_launch(void* const* d_in, const int* in_sizes, int n_in,
                              void* d_out, int out_size, void* d_ws, size_t ws_size,
                              hipStream_t stream)
{
    const float* x  = (const float*)d_in[0];
    const float* Wu = (const float*)d_in[1];
    const float* bu = (const float*)d_in[2];
    const float* Wv = (const float*)d_in[3];
    const float* bv = (const float*)d_in[4];
    const float* Wo = (const float*)d_in[5];
    const float* bo = (const float*)d_in[6];
    const float* Wp = (const float*)d_in[7];
    const float* bp = (const float*)d_in[8];
    const float* Wl = (const float*)d_in[9];
    const float* bl = (const float*)d_in[10];
    const float* Wr = (const float*)d_in[11];
    const float* br = (const float*)d_in[12];
    float* out = (float*)d_out;

    float* ws      = (float*)d_ws;
    float* a_t     = ws;                       // 1536*4096 fp32
    float* Wspec   = a_t   + 6291456;          // 768 x 4096 float2
    float* h0      = Wspec + 6291456;          // 4096*512 fp32
    bf16*  bfws    = (bf16*)(h0 + 2097152);
    bf16*  x_bf    = bfws;                     // 8192*512
    bf16*  w_bf    = x_bf    + 4194304;        // 5 x 786432: Wu,Wv,Wo,Wl,Wr
    bf16*  Wu_bf   = w_bf;
    bf16*  Wv_bf   = Wu_bf   + 786432;
    bf16*  Wo_bf   = Wv_bf   + 786432;
    bf16*  Wl_bf   = Wo_bf   + 786432;
    bf16*  Wr_bf   = Wl_bf   + 786432;
    bf16*  g_bf    = Wr_bf   + 786432;         // 4096*512
    bf16*  u_t     = g_bf    + 2097152;        // 8192*1536 [b][c][s]
    bf16*  v_t     = u_t     + 12582912;       // 8192*1536 [b][c][s]
    bf16*  gated_t = v_t     + 12582912;       // 8192*1536 [b][c][s]
    bf16*  gated   = gated_t + 12582912;       // 8192*1536 [m][c]

    dim3 blk(256);

    f2b_kernel<<<4194304 / 1024, blk, 0, stream>>>(x, x_bf, 4194304);
    f2b5_kernel<<<dim3(786432 / 1024, 5), blk, 0, stream>>>(
        Wu, Wv, Wo, Wl, Wr, w_bf);

    gemm_bf16<MODE_SILU_VT, bf16><<<dim3(12, 64), blk, 0, stream>>>(
        x_bf, Wu_bf, bu, u_t, 8192, D1, ED);
    gemm_bf16<MODE_SILU_VT, bf16><<<dim3(12, 64), blk, 0, stream>>>(
        x_bf, Wv_bf, bv, v_t, 8192, D1, ED);

    rpe_in_srms_kernel<<<4096, blk, 0, stream>>>(Wp, bp, g_bf);
    for (int i = 0; i < 3; ++i) {
        gemm_bf16<MODE_PLAIN, float><<<dim3(4, 32), blk, 0, stream>>>(
            g_bf, Wl_bf + (size_t)i * ED * ED, bl + (size_t)i * ED,
            h0, 4096, ED, ED);
        srms_relu_kernel<<<4096, blk, 0, stream>>>(h0, g_bf);
    }
    gemm_bf16<MODE_AT, float><<<dim3(12, 32), blk, 0, stream>>>(
        g_bf, Wr_bf, br, a_t, 4096, D1, ED);

    fft_a_kernel<<<768, blk, 0, stream>>>(a_t, (float2*)Wspec);
    fft_conv_kernel<<<3072, blk, 0, stream>>>(
        v_t, (const float2*)Wspec, u_t, gated_t);

    transpose_cs_kernel<<<dim3(24, 128), blk, 0, stream>>>(gated_t, gated);

    gemm_bf16<MODE_PLAIN, float><<<dim3(4, 64), blk, 0, stream>>>(
        gated, Wo_bf, bo, out, 8192, ED, D1);
}

// Round 6
// 378.279 us; speedup vs baseline: 3.1409x; 1.0064x over previous
//
#include <hip/hip_runtime.h>

#define N_SEQ 2048
#define M_FFT 4096
#define D1    1536
#define NH    8
#define HD    192
#define ED    512

typedef __bf16 bf16;
typedef __bf16 bf16x2 __attribute__((ext_vector_type(2)));
typedef __bf16 bf16x4 __attribute__((ext_vector_type(4)));
typedef __bf16 bf16x8 __attribute__((ext_vector_type(8)));
typedef float  floatx4 __attribute__((ext_vector_type(4)));

enum { MODE_PLAIN = 0, MODE_SILU_UV = 1, MODE_AT = 3 };

__device__ __forceinline__ void gload16(const void* g, void* l) {
    __builtin_amdgcn_global_load_lds(
        (const __attribute__((address_space(1))) void*)g,
        (__attribute__((address_space(3))) void*)l, 16, 0, 0);
}

// ---------------------------------------------------------------------------
// bf16 MFMA GEMM (m97 structure): C = epilogue(A(MxK) @ Bw(NcxK)^T + bias)
// MODE_SILU_UV: cols [0,1536) -> silu -> C ([b][c][s] bf16), cols [1536,3072)
//               -> silu -> C2 (same layout); bias/bias2 accordingly.
// ---------------------------------------------------------------------------
template<int MODE, typename OutT>
__global__ __launch_bounds__(256) void gemm_bf16(
    const bf16* __restrict__ A, const bf16* __restrict__ Bw,
    const float* __restrict__ bias, const float* __restrict__ bias2,
    OutT* __restrict__ C, OutT* __restrict__ C2,
    int M, int Nc, int K)
{
    __shared__ __align__(16) bf16 As[128 * 32];
    __shared__ __align__(16) bf16 Bs[128 * 32];

    const int tid  = threadIdx.x;
    const int row0 = blockIdx.y * 128;
    const int col0 = blockIdx.x * 128;
    const int wid  = tid >> 6;
    const int lane = tid & 63;
    const int lm   = lane & 15;
    const int lk   = lane >> 4;
    const int wm   = wid >> 1;
    const int wn   = wid & 1;
    const int ldrow  = tid >> 2;
    const int ldcol8 = (tid & 3) * 8;

    floatx4 acc[4][4] = {};

    const bf16* Ag = A  + ((size_t)(row0 + ldrow)) * K + ldcol8;
    const bf16* Bg = Bw + ((size_t)(col0 + ldrow)) * K + ldcol8;
    bf16* AsW = As + (wid * 16) * 32;
    bf16* BsW = Bs + (wid * 16) * 32;

    for (int k0 = 0; k0 < K; k0 += 32) {
        gload16(Ag + k0, AsW);
        gload16(Ag + (size_t)64 * K + k0, AsW + 64 * 32);
        gload16(Bg + k0, BsW);
        gload16(Bg + (size_t)64 * K + k0, BsW + 64 * 32);
        __syncthreads();

        bf16x8 af[4], bfr[4];
        #pragma unroll
        for (int mi = 0; mi < 4; ++mi)
            af[mi] = *(const bf16x8*)&As[(wm * 64 + mi * 16 + lm) * 32 + lk * 8];
        #pragma unroll
        for (int nj = 0; nj < 4; ++nj)
            bfr[nj] = *(const bf16x8*)&Bs[(wn * 64 + nj * 16 + lm) * 32 + lk * 8];
        #pragma unroll
        for (int mi = 0; mi < 4; ++mi)
            #pragma unroll
            for (int nj = 0; nj < 4; ++nj)
                acc[mi][nj] = __builtin_amdgcn_mfma_f32_16x16x32_bf16(
                    af[mi], bfr[nj], acc[mi][nj], 0, 0, 0);
        __syncthreads();
    }

    // MODE_SILU_UV routing (block-uniform: 1536 % 128 == 0)
    const float* bs = bias;
    OutT* dst = C;
    int cadj = 0;
    if (MODE == MODE_SILU_UV && col0 >= D1) { bs = bias2; dst = C2; cadj = D1; }

    float bcol[4];
    #pragma unroll
    for (int nj = 0; nj < 4; ++nj)
        bcol[nj] = bs[col0 - cadj + wn * 64 + nj * 16 + lm];

    #pragma unroll
    for (int mi = 0; mi < 4; ++mi) {
        const int rbase = row0 + wm * 64 + mi * 16 + lk * 4;
        #pragma unroll
        for (int nj = 0; nj < 4; ++nj) {
            const int col = col0 - cadj + wn * 64 + nj * 16 + lm;
            float vals[4];
            #pragma unroll
            for (int r = 0; r < 4; ++r) {
                float val = acc[mi][nj][r] + bcol[nj];
                if (MODE == MODE_SILU_UV)
                    val = val / (1.0f + __expf(-val));
                vals[r] = val;
            }
            if (MODE == MODE_SILU_UV) {
                int b = rbase >> 11, s = rbase & 2047;
                bf16x4 o;
                #pragma unroll
                for (int r = 0; r < 4; ++r) o[r] = (bf16)vals[r];
                *(bf16x4*)&((bf16*)dst)[((size_t)(b * D1 + col)) * N_SEQ + s] = o;
            } else if (MODE == MODE_AT) {
                float4 o = make_float4(vals[0], vals[1], vals[2], vals[3]);
                *(float4*)&((float*)C)[(size_t)col * M + rbase] = o;
            } else {
                #pragma unroll
                for (int r = 0; r < 4; ++r)
                    C[(size_t)(rbase + r) * Nc + col] = (OutT)vals[r];
            }
        }
    }
}

// ---------------------------------------------------------------------------
__global__ __launch_bounds__(256) void f2b_kernel(
    const float* __restrict__ in, bf16* __restrict__ out, int n)
{
    int i = (blockIdx.x * 256 + threadIdx.x) * 4;
    if (i >= n) return;
    float4 f = *(const float4*)(in + i);
    union { bf16 h[4]; short4 s; } u4;
    u4.h[0] = (bf16)f.x; u4.h[1] = (bf16)f.y;
    u4.h[2] = (bf16)f.z; u4.h[3] = (bf16)f.w;
    *(short4*)(out + i) = u4.s;
}

__global__ __launch_bounds__(256) void f2b5_kernel(
    const float* __restrict__ s0, const float* __restrict__ s1,
    const float* __restrict__ s2, const float* __restrict__ s3,
    const float* __restrict__ s4, bf16* __restrict__ dst)
{
    const int seg = blockIdx.y;
    const float* src = seg == 0 ? s0 : seg == 1 ? s1 : seg == 2 ? s2
                     : seg == 3 ? s3 : s4;
    int i = (blockIdx.x * 256 + threadIdx.x) * 4;
    float4 f = *(const float4*)(src + i);
    union { bf16 h[4]; short4 s; } u4;
    u4.h[0] = (bf16)f.x; u4.h[1] = (bf16)f.y;
    u4.h[2] = (bf16)f.z; u4.h[3] = (bf16)f.w;
    *(short4*)(dst + (size_t)seg * 786432 + i) = u4.s;
}

// ---------------------------------------------------------------------------
__global__ __launch_bounds__(256) void rpe_in_srms_kernel(
    const float* __restrict__ Wp, const float* __restrict__ bp,
    bf16* __restrict__ g)
{
    const int j = blockIdx.x;
    const int tid = threadIdx.x;
    float idxv = (j < N_SEQ) ? (float)j
                             : (j == N_SEQ ? 0.0f : (float)(j - 2 * N_SEQ));
    float h1 = idxv * Wp[tid] + bp[tid];
    float h2 = idxv * Wp[tid + 256] + bp[tid + 256];
    float ss = h1 * h1 + h2 * h2;
    #pragma unroll
    for (int off = 32; off > 0; off >>= 1) ss += __shfl_down(ss, off, 64);
    __shared__ float red[4];
    if ((tid & 63) == 0) red[tid >> 6] = ss;
    __syncthreads();
    float tot = red[0] + red[1] + red[2] + red[3];
    float scale = 1.0f / (sqrtf(tot) * 0.04419417382415922f + 1e-8f);
    g[(size_t)j * ED + tid]       = (bf16)fmaxf(h1 * scale, 0.0f);
    g[(size_t)j * ED + tid + 256] = (bf16)fmaxf(h2 * scale, 0.0f);
}

__global__ __launch_bounds__(256) void srms_relu_kernel(
    const float* __restrict__ in, bf16* __restrict__ out)
{
    const int row = blockIdx.x;
    const int tid = threadIdx.x;
    const float* p = in + (size_t)row * ED;

    float ss = 0.0f;
    for (int i = tid; i < ED; i += 256) { float x = p[i]; ss += x * x; }
    #pragma unroll
    for (int off = 32; off > 0; off >>= 1) ss += __shfl_down(ss, off, 64);
    __shared__ float red[4];
    if ((tid & 63) == 0) red[tid >> 6] = ss;
    __syncthreads();
    float tot = red[0] + red[1] + red[2] + red[3];
    float scale = 1.0f / (sqrtf(tot) * 0.04419417382415922f + 1e-8f);
    for (int i = tid; i < ED; i += 256)
        out[(size_t)row * ED + i] = (bf16)fmaxf(p[i] * scale, 0.0f);
}

// ---------------------------------------------------------------------------
// Radix-16 FFT, radix-4-factored butterflies. 4096 = 16^3.
// ---------------------------------------------------------------------------
#define FFT_LDS_SZ 4381
#define CC1 0.9238795325112867f
#define SS1 0.3826834323650898f
#define RR2 0.7071067811865476f

__device__ __forceinline__ int fpad(int i) { return i + (i >> 4) + 2 * (i >> 8); }

__device__ __forceinline__ float2 cmul(float2 a, float2 b) {
    return make_float2(a.x * b.x - a.y * b.y, a.x * b.y + a.y * b.x);
}
__device__ __forceinline__ float2 cadd(float2 a, float2 b) {
    return make_float2(a.x + b.x, a.y + b.y);
}
__device__ __forceinline__ float2 csub(float2 a, float2 b) {
    return make_float2(a.x - b.x, a.y - b.y);
}
__device__ __forceinline__ float2 cneg_i(float2 a) { return make_float2(a.y, -a.x); }  // a * (-i)
__device__ __forceinline__ float2 cpos_i(float2 a) { return make_float2(-a.y, a.x); }  // a * (+i)
__host__ __device__ constexpr int brev4(int t) {
    return ((t & 1) << 3) | ((t & 2) << 1) | ((t & 4) >> 1) | ((t & 8) >> 3);
}

// forward 16-pt DIF, radix-4 factored; natural in -> brev4 out.
// If HZ, x[8..15] are implicitly zero (not read).
template<bool HZ>
__device__ __forceinline__ void fft16_dif_r4(float2 x[16]) {
    const float2 W1 = make_float2( CC1, -SS1);
    const float2 W2 = make_float2( RR2, -RR2);
    const float2 W3 = make_float2( SS1, -CC1);
    const float2 W6 = make_float2(-RR2, -RR2);
    const float2 W9 = make_float2(-CC1,  SS1);
    // levels 1+2: groups (n, n+4, n+8, n+12); tw: w[2n] on +4, w[n] on +8, w[3n] on +12
    #pragma unroll
    for (int n = 0; n < 4; ++n) {
        float2 A, B, C, D;
        if (HZ) { A = x[n]; C = x[n]; B = x[n + 4]; D = x[n + 4]; }
        else {
            A = cadd(x[n], x[n + 8]);  C = csub(x[n], x[n + 8]);
            B = cadd(x[n + 4], x[n + 12]); D = csub(x[n + 4], x[n + 12]);
        }
        float2 s = csub(A, B);
        float2 nid = cneg_i(D);
        float2 m = cadd(C, nid);   // C - iD
        float2 p = csub(C, nid);   // C + iD
        x[n] = cadd(A, B);
        if (n == 0)      { x[4] = s;            x[8]  = m;           x[12] = p; }
        else if (n == 1) { x[5] = cmul(s, W2);  x[9]  = cmul(m, W1); x[13] = cmul(p, W3); }
        else if (n == 2) { x[6] = cneg_i(s);    x[10] = cmul(m, W2); x[14] = cmul(p, W6); }
        else             { x[7] = cmul(s, W6);  x[11] = cmul(m, W3); x[15] = cmul(p, W9); }
    }
    // levels 3+4: quads, twiddle-free
    #pragma unroll
    for (int q = 0; q < 16; q += 4) {
        float2 a = x[q], b = x[q + 1], c = x[q + 2], d = x[q + 3];
        float2 a1 = cadd(a, c), c1 = csub(a, c);
        float2 b1 = cadd(b, d), d1 = cneg_i(csub(b, d));
        x[q]     = cadd(a1, b1);
        x[q + 1] = csub(a1, b1);
        x[q + 2] = cadd(c1, d1);
        x[q + 3] = csub(c1, d1);
    }
}

// inverse 16-pt DIT (conj twiddles), brev4 in -> natural out, scaled x16.
// If HALF_OUT, outputs 8..15 are not produced.
template<bool HALF_OUT>
__device__ __forceinline__ void fft16_dit_inv_r4(float2 x[16]) {
    const float2 V1 = make_float2( CC1, SS1);
    const float2 V2 = make_float2( RR2, RR2);
    const float2 V3 = make_float2( SS1, CC1);
    const float2 V6 = make_float2(-RR2, RR2);
    // levels 1+2: quads, twiddle-free
    #pragma unroll
    for (int q = 0; q < 16; q += 4) {
        float2 a = x[q], b = x[q + 1], c = x[q + 2], d = x[q + 3];
        float2 a1 = cadd(a, b), b1 = csub(a, b);
        float2 c1 = cadd(c, d), d1 = csub(c, d);
        float2 t = cpos_i(d1);
        x[q]     = cadd(a1, c1);
        x[q + 2] = csub(a1, c1);
        x[q + 1] = cadd(b1, t);
        x[q + 3] = csub(b1, t);
    }
    // levels 3+4: groups (n, n+4, n+8, n+12); tw conj w[2n] then conj w[n]
    #pragma unroll
    for (int n = 0; n < 4; ++n) {
        float2 t1, t2;
        if (n == 0)      { t1 = x[4];             t2 = x[12]; }
        else if (n == 1) { t1 = cmul(x[5],  V2);  t2 = cmul(x[13], V2); }
        else if (n == 2) { t1 = cpos_i(x[6]);     t2 = cpos_i(x[14]); }
        else             { t1 = cmul(x[7],  V6);  t2 = cmul(x[15], V6); }
        float2 P = cadd(x[n], t1), Q = csub(x[n], t1);
        float2 R = cadd(x[n + 8], t2), S = csub(x[n + 8], t2);
        float2 t, u;
        if (n == 0)      { t = R;            u = S; }
        else if (n == 1) { t = cmul(R, V1);  u = cmul(S, V1); }
        else if (n == 2) { t = cmul(R, V2);  u = cmul(S, V2); }
        else             { t = cmul(R, V3);  u = cmul(S, V3); }
        float2 iu = cpos_i(u);
        x[n]     = cadd(P, t);
        x[n + 4] = cadd(Q, iu);
        if (!HALF_OUT) {
            x[n + 8]  = csub(P, t);
            x[n + 12] = csub(Q, iu);
        }
    }
}

// twl[k] = e^{-2*pi*i*k/4096}, k in [0,2048)
__device__ __forceinline__ void build_twl(float2* twl, int tid)
{
    for (int k = tid; k < 2048; k += 256) {
        float sn, cs;
        __sincosf(-6.283185307179586f * (float)k * (1.0f / 4096.0f), &sn, &cs);
        twl[k] = make_float2(cs, sn);
    }
}

// v[brev4(tau)] *= W4096^{j*tau*mult}  (conj if CONJ). j*tau*mult < 4096.
template<bool CONJ>
__device__ __forceinline__ void stage_twiddle_tab(
    float2 v[16], const float2* __restrict__ twl, int j, int mult)
{
    #pragma unroll
    for (int tau = 1; tau < 16; ++tau) {
        int m = j * tau * mult;
        float2 t = twl[m & 2047];
        float sg = (m & 2048) ? -1.0f : 1.0f;
        t.x *= sg;
        t.y = CONJ ? -t.y * sg : t.y * sg;
        v[brev4(tau)] = cmul(v[brev4(tau)], t);
    }
}

template<bool HALF_ZERO>
__device__ void fft4096_fwd(float2* d, const float2* twl, int tid)
{
    float2 v[16];
    {   // stage 1: span 256
        const int j = tid;
        if (HALF_ZERO) {
            #pragma unroll
            for (int t = 0; t < 8; ++t) v[t] = d[fpad(j + (t << 8))];
            fft16_dif_r4<true>(v);
        } else {
            #pragma unroll
            for (int t = 0; t < 16; ++t) v[t] = d[fpad(j + (t << 8))];
            fft16_dif_r4<false>(v);
        }
        stage_twiddle_tab<false>(v, twl, j, 1);
        #pragma unroll
        for (int p = 0; p < 16; ++p) d[fpad(j + (p << 8))] = v[p];
    }
    __syncthreads();
    {   // stage 2: span 16
        const int base = ((tid >> 4) << 8) + (tid & 15);
        #pragma unroll
        for (int t = 0; t < 16; ++t) v[t] = d[fpad(base + (t << 4))];
        fft16_dif_r4<false>(v);
        stage_twiddle_tab<false>(v, twl, tid & 15, 16);
        #pragma unroll
        for (int p = 0; p < 16; ++p) d[fpad(base + (p << 4))] = v[p];
    }
    __syncthreads();
    {   // stage 3: contiguous 16
        const int base = tid << 4;
        #pragma unroll
        for (int t = 0; t < 16; ++t) v[t] = d[fpad(base + t)];
        fft16_dif_r4<false>(v);
        #pragma unroll
        for (int p = 0; p < 16; ++p) d[fpad(base + p)] = v[p];
    }
    __syncthreads();
}

template<bool HALF_OUT>
__device__ void fft4096_inv(float2* d, const float2* twl, int tid)
{
    float2 v[16];
    {
        const int base = tid << 4;
        #pragma unroll
        for (int p = 0; p < 16; ++p) v[p] = d[fpad(base + p)];
        fft16_dit_inv_r4<false>(v);
        #pragma unroll
        for (int t = 0; t < 16; ++t) d[fpad(base + t)] = v[t];
    }
    __syncthreads();
    {
        const int base = ((tid >> 4) << 8) + (tid & 15);
        #pragma unroll
        for (int p = 0; p < 16; ++p) v[p] = d[fpad(base + (p << 4))];
        stage_twiddle_tab<true>(v, twl, tid & 15, 16);
        fft16_dit_inv_r4<false>(v);
        #pragma unroll
        for (int t = 0; t < 16; ++t) d[fpad(base + (t << 4))] = v[t];
    }
    __syncthreads();
    {
        const int j = tid;
        #pragma unroll
        for (int p = 0; p < 16; ++p) v[p] = d[fpad(j + (p << 8))];
        stage_twiddle_tab<true>(v, twl, j, 1);
        fft16_dit_inv_r4<HALF_OUT>(v);
        #pragma unroll
        for (int t = 0; t < (HALF_OUT ? 8 : 16); ++t) d[fpad(j + (t << 8))] = v[t];
    }
    __syncthreads();
}

// ---------------------------------------------------------------------------
__global__ __launch_bounds__(256) void fft_a_kernel(
    const float* __restrict__ a_t, float2* __restrict__ Wspec)
{
    __shared__ float2 data[FFT_LDS_SZ];
    __shared__ float2 twl[2048];
    const int tid = threadIdx.x;
    const int h = blockIdx.x / 96, dp = blockIdx.x % 96;

    const float* r0 = a_t + ((size_t)(h * HD + 2 * dp)) * M_FFT;
    const float* r1 = r0 + M_FFT;

    build_twl(twl, tid);
    for (int j = tid; j < 4096; j += 256) data[fpad(j)] = make_float2(r0[j], r1[j]);
    __syncthreads();
    fft4096_fwd<false>(data, twl, tid);

    float2* outrow = Wspec + (size_t)blockIdx.x * 4096;
    for (int j = tid; j < 4096; j += 256) outrow[j] = data[fpad(j)];
}

// ---------------------------------------------------------------------------
__global__ __launch_bounds__(256) void fft_conv_kernel(
    const bf16* __restrict__ v_t, const float2* __restrict__ Wspec,
    const bf16* __restrict__ u_t, bf16* __restrict__ gated_t)
{
    __shared__ float2 data[FFT_LDS_SZ];
    __shared__ float2 twl[2048];
    const int tid = threadIdx.x;
    const int bx = blockIdx.x;
    const int b  = bx / 768;
    const int r  = bx % 768;
    const int h  = r / 96, dp = r % 96;
    const int ch = h * HD + 2 * dp;

    const bf16* z0 = v_t + ((size_t)(b * D1 + ch)) * N_SEQ;
    const bf16* z1 = z0 + N_SEQ;

    build_twl(twl, tid);
    {
        const int s = tid * 8;
        bf16x8 a0 = *(const bf16x8*)(z0 + s);
        bf16x8 a1 = *(const bf16x8*)(z1 + s);
        #pragma unroll
        for (int i = 0; i < 8; ++i)
            data[fpad(s + i)] = make_float2((float)a0[i], (float)a1[i]);
    }
    __syncthreads();

    fft4096_fwd<true>(data, twl, tid);

    const float2* Wrow = Wspec + (size_t)r * 4096;
    for (int k = tid; k <= 2048; k += 256) {
        int km = (4096 - k) & 4095;
        int p1 = __brev((unsigned)k)  >> 20;
        int p2 = __brev((unsigned)km) >> 20;
        float2 Zk = data[fpad(p1)], Zm = data[fpad(p2)];
        float2 Wk = Wrow[p1], Wm = Wrow[p2];
        float2 V0 = make_float2(0.5f * (Zk.x + Zm.x), 0.5f * (Zk.y - Zm.y));
        float2 V1 = make_float2(0.5f * (Zk.y + Zm.y), 0.5f * (Zm.x - Zk.x));
        float2 A0 = make_float2(0.5f * (Wk.x + Wm.x), 0.5f * (Wk.y - Wm.y));
        float2 A1 = make_float2(0.5f * (Wk.y + Wm.y), 0.5f * (Wm.x - Wk.x));
        float2 P = make_float2(V0.x * A0.x - V0.y * A0.y, V0.x * A0.y + V0.y * A0.x);
        float2 Q = make_float2(V1.x * A1.x - V1.y * A1.y, V1.x * A1.y + V1.y * A1.x);
        data[fpad(p1)] = make_float2(P.x - Q.y, P.y + Q.x);
        if (k != 0 && k != 2048)
            data[fpad(p2)] = make_float2(P.x + Q.y, Q.x - P.y);
    }
    __syncthreads();

    fft4096_inv<true>(data, twl, tid);

    const float inv_m = 1.0f / 4096.0f;
    const bf16* u0 = u_t + ((size_t)(b * D1 + ch)) * N_SEQ;
    const bf16* u1 = u0 + N_SEQ;
    bf16* g0 = gated_t + ((size_t)(b * D1 + ch)) * N_SEQ;
    bf16* g1 = g0 + N_SEQ;
    {
        const int t = tid * 8;
        bf16x8 ua = *(const bf16x8*)(u0 + t);
        bf16x8 ub = *(const bf16x8*)(u1 + t);
        bf16x8 oa, ob;
        #pragma unroll
        for (int i = 0; i < 8; ++i) {
            float2 y = data[fpad(t + i)];
            oa[i] = (bf16)(y.x * inv_m * (float)ua[i]);
            ob[i] = (bf16)(y.y * inv_m * (float)ub[i]);
        }
        *(bf16x8*)(g0 + t) = oa;
        *(bf16x8*)(g1 + t) = ob;
    }
}

// ---------------------------------------------------------------------------
__global__ __launch_bounds__(256) void transpose_cs_kernel(
    const bf16* __restrict__ in, bf16* __restrict__ outp)
{
    __shared__ bf16 tile[64 * 68];
    const int c0 = blockIdx.x * 64;
    const int m0 = blockIdx.y * 64;
    const int b  = m0 >> 11;
    const int s0 = m0 & 2047;
    const int tid = threadIdx.x;
    const int cl = tid >> 4;
    const int sc = (tid & 15) * 4;
    #pragma unroll
    for (int p = 0; p < 4; ++p) {
        int c = p * 16 + cl;
        bf16x4 v = *(const bf16x4*)&in[((size_t)(b * D1 + c0 + c)) * N_SEQ + s0 + sc];
        *(bf16x4*)&tile[c * 68 + sc] = v;
    }
    __syncthreads();
    const int sl = tid >> 4;
    const int cc = (tid & 15) * 4;
    #pragma unroll
    for (int p = 0; p < 4; ++p) {
        int s = p * 16 + sl;
        bf16x4 o;
        #pragma unroll
        for (int j = 0; j < 4; ++j) o[j] = tile[(cc + j) * 68 + s];
        *(bf16x4*)&outp[((size_t)(m0 + s)) * D1 + c0 + cc] = o;
    }
}

// ---------------------------------------------------------------------------
extern "C" void kernel_launch(void* const* d_in, const int* in_sizes, int n_in,
                              void* d_out, int out_size, void* d_ws, size_t ws_size,
                              hipStream_t stream)
{
    const float* x  = (const float*)d_in[0];
    const float* Wu = (const float*)d_in[1];
    const float* bu = (const float*)d_in[2];
    const float* Wv = (const float*)d_in[3];
    const float* bv = (const float*)d_in[4];
    const float* Wo = (const float*)d_in[5];
    const float* bo = (const float*)d_in[6];
    const float* Wp = (const float*)d_in[7];
    const float* bp = (const float*)d_in[8];
    const float* Wl = (const float*)d_in[9];
    const float* bl = (const float*)d_in[10];
    const float* Wr = (const float*)d_in[11];
    const float* br = (const float*)d_in[12];
    float* out = (float*)d_out;

    float* ws      = (float*)d_ws;
    float* a_t     = ws;                       // 1536*4096 fp32
    float* Wspec   = a_t   + 6291456;          // 768 x 4096 float2
    float* h0      = Wspec + 6291456;          // 4096*512 fp32
    bf16*  bfws    = (bf16*)(h0 + 2097152);
    bf16*  x_bf    = bfws;                     // 8192*512
    bf16*  w_bf    = x_bf    + 4194304;        // 5 x 786432: Wu,Wv,Wo,Wl,Wr
    bf16*  Wuv_bf  = w_bf;                     // stacked [Wu;Wv] 3072 x 512
    bf16*  Wo_bf   = w_bf    + 2 * 786432;
    bf16*  Wl_bf   = Wo_bf   + 786432;
    bf16*  Wr_bf   = Wl_bf   + 786432;
    bf16*  g_bf    = Wr_bf   + 786432;         // 4096*512
    bf16*  u_t     = g_bf    + 2097152;        // 8192*1536 [b][c][s]
    bf16*  v_t     = u_t     + 12582912;       // 8192*1536 [b][c][s]
    bf16*  gated_t = v_t     + 12582912;       // 8192*1536 [b][c][s]
    bf16*  gated   = gated_t + 12582912;       // 8192*1536 [m][c]

    dim3 blk(256);

    f2b_kernel<<<4194304 / 1024, blk, 0, stream>>>(x, x_bf, 4194304);
    f2b5_kernel<<<dim3(786432 / 1024, 5), blk, 0, stream>>>(
        Wu, Wv, Wo, Wl, Wr, w_bf);

    // fused u|v GEMM over stacked weights: cols [0,1536)->u_t, [1536,3072)->v_t
    gemm_bf16<MODE_SILU_UV, bf16><<<dim3(24, 64), blk, 0, stream>>>(
        x_bf, Wuv_bf, bu, bv, u_t, v_t, 8192, 2 * D1, ED);

    rpe_in_srms_kernel<<<4096, blk, 0, stream>>>(Wp, bp, g_bf);
    for (int i = 0; i < 3; ++i) {
        gemm_bf16<MODE_PLAIN, float><<<dim3(4, 32), blk, 0, stream>>>(
            g_bf, Wl_bf + (size_t)i * ED * ED, bl + (size_t)i * ED, nullptr,
            h0, nullptr, 4096, ED, ED);
        srms_relu_kernel<<<4096, blk, 0, stream>>>(h0, g_bf);
    }
    gemm_bf16<MODE_AT, float><<<dim3(12, 32), blk, 0, stream>>>(
        g_bf, Wr_bf, br, nullptr, a_t, nullptr, 4096, D1, ED);

    fft_a_kernel<<<768, blk, 0, stream>>>(a_t, (float2*)Wspec);
    fft_conv_kernel<<<3072, blk, 0, stream>>>(
        v_t, (const float2*)Wspec, u_t, gated_t);

    transpose_cs_kernel<<<dim3(24, 128), blk, 0, stream>>>(gated_t, gated);

    gemm_bf16<MODE_PLAIN, float><<<dim3(4, 64), blk, 0, stream>>>(
        gated, Wo_bf, bo, nullptr, out, nullptr, 8192, ED, D1);
}

// Round 7
// 365.529 us; speedup vs baseline: 3.2504x; 1.0349x over previous
//
#include <hip/hip_runtime.h>

#define N_SEQ 2048
#define M_FFT 4096
#define D1    1536
#define NH    8
#define HD    192
#define ED    512

typedef __bf16 bf16;
typedef __bf16 bf16x2 __attribute__((ext_vector_type(2)));
typedef __bf16 bf16x4 __attribute__((ext_vector_type(4)));
typedef __bf16 bf16x8 __attribute__((ext_vector_type(8)));
typedef float  floatx4 __attribute__((ext_vector_type(4)));

enum { MODE_PLAIN = 0, MODE_SILU_UV = 1, MODE_AT = 3 };

__device__ __forceinline__ void gload16(const void* g, void* l) {
    __builtin_amdgcn_global_load_lds(
        (const __attribute__((address_space(1))) void*)g,
        (__attribute__((address_space(3))) void*)l, 16, 0, 0);
}

// ---------------------------------------------------------------------------
// bf16 MFMA GEMM (m97 structure): C = epilogue(A(MxK) @ Bw(NcxK)^T + bias)
// ---------------------------------------------------------------------------
template<int MODE, typename OutT>
__global__ __launch_bounds__(256) void gemm_bf16(
    const bf16* __restrict__ A, const bf16* __restrict__ Bw,
    const float* __restrict__ bias, const float* __restrict__ bias2,
    OutT* __restrict__ C, OutT* __restrict__ C2,
    int M, int Nc, int K)
{
    __shared__ __align__(16) bf16 As[128 * 32];
    __shared__ __align__(16) bf16 Bs[128 * 32];

    const int tid  = threadIdx.x;
    const int row0 = blockIdx.y * 128;
    const int col0 = blockIdx.x * 128;
    const int wid  = tid >> 6;
    const int lane = tid & 63;
    const int lm   = lane & 15;
    const int lk   = lane >> 4;
    const int wm   = wid >> 1;
    const int wn   = wid & 1;
    const int ldrow  = tid >> 2;
    const int ldcol8 = (tid & 3) * 8;

    floatx4 acc[4][4] = {};

    const bf16* Ag = A  + ((size_t)(row0 + ldrow)) * K + ldcol8;
    const bf16* Bg = Bw + ((size_t)(col0 + ldrow)) * K + ldcol8;
    bf16* AsW = As + (wid * 16) * 32;
    bf16* BsW = Bs + (wid * 16) * 32;

    for (int k0 = 0; k0 < K; k0 += 32) {
        gload16(Ag + k0, AsW);
        gload16(Ag + (size_t)64 * K + k0, AsW + 64 * 32);
        gload16(Bg + k0, BsW);
        gload16(Bg + (size_t)64 * K + k0, BsW + 64 * 32);
        __syncthreads();

        bf16x8 af[4], bfr[4];
        #pragma unroll
        for (int mi = 0; mi < 4; ++mi)
            af[mi] = *(const bf16x8*)&As[(wm * 64 + mi * 16 + lm) * 32 + lk * 8];
        #pragma unroll
        for (int nj = 0; nj < 4; ++nj)
            bfr[nj] = *(const bf16x8*)&Bs[(wn * 64 + nj * 16 + lm) * 32 + lk * 8];
        #pragma unroll
        for (int mi = 0; mi < 4; ++mi)
            #pragma unroll
            for (int nj = 0; nj < 4; ++nj)
                acc[mi][nj] = __builtin_amdgcn_mfma_f32_16x16x32_bf16(
                    af[mi], bfr[nj], acc[mi][nj], 0, 0, 0);
        __syncthreads();
    }

    const float* bs = bias;
    OutT* dst = C;
    int cadj = 0;
    if (MODE == MODE_SILU_UV && col0 >= D1) { bs = bias2; dst = C2; cadj = D1; }

    float bcol[4];
    #pragma unroll
    for (int nj = 0; nj < 4; ++nj)
        bcol[nj] = bs[col0 - cadj + wn * 64 + nj * 16 + lm];

    #pragma unroll
    for (int mi = 0; mi < 4; ++mi) {
        const int rbase = row0 + wm * 64 + mi * 16 + lk * 4;
        #pragma unroll
        for (int nj = 0; nj < 4; ++nj) {
            const int col = col0 - cadj + wn * 64 + nj * 16 + lm;
            float vals[4];
            #pragma unroll
            for (int r = 0; r < 4; ++r) {
                float val = acc[mi][nj][r] + bcol[nj];
                if (MODE == MODE_SILU_UV)
                    val = val / (1.0f + __expf(-val));
                vals[r] = val;
            }
            if (MODE == MODE_SILU_UV) {
                int b = rbase >> 11, s = rbase & 2047;
                bf16x4 o;
                #pragma unroll
                for (int r = 0; r < 4; ++r) o[r] = (bf16)vals[r];
                *(bf16x4*)&((bf16*)dst)[((size_t)(b * D1 + col)) * N_SEQ + s] = o;
            } else if (MODE == MODE_AT) {
                float4 o = make_float4(vals[0], vals[1], vals[2], vals[3]);
                *(float4*)&((float*)C)[(size_t)col * M + rbase] = o;
            } else {
                #pragma unroll
                for (int r = 0; r < 4; ++r)
                    C[(size_t)(rbase + r) * Nc + col] = (OutT)vals[r];
            }
        }
    }
}

// ---------------------------------------------------------------------------
// merged fp32->bf16 converts: x (4096 blocks) + 5 weight blobs (5*768 blocks)
// ---------------------------------------------------------------------------
__global__ __launch_bounds__(256) void f2b_all_kernel(
    const float* __restrict__ x,  const float* __restrict__ s0,
    const float* __restrict__ s1, const float* __restrict__ s2,
    const float* __restrict__ s3, const float* __restrict__ s4,
    bf16* __restrict__ x_bf, bf16* __restrict__ w_bf)
{
    const int bid = blockIdx.x;
    const float* src;
    bf16* dst;
    size_t off;
    if (bid < 4096) {
        src = x; dst = x_bf; off = (size_t)bid * 1024;
    } else {
        int t = bid - 4096;
        int seg = t / 768;
        src = seg == 0 ? s0 : seg == 1 ? s1 : seg == 2 ? s2 : seg == 3 ? s3 : s4;
        dst = w_bf + (size_t)seg * 786432;
        off = (size_t)(t % 768) * 1024;
    }
    size_t i = off + (size_t)threadIdx.x * 4;
    float4 f = *(const float4*)(src + i);
    union { bf16 h[4]; short4 s; } u4;
    u4.h[0] = (bf16)f.x; u4.h[1] = (bf16)f.y;
    u4.h[2] = (bf16)f.z; u4.h[3] = (bf16)f.w;
    *(short4*)(dst + i) = u4.s;
}

// ---------------------------------------------------------------------------
__global__ __launch_bounds__(256) void rpe_in_srms_kernel(
    const float* __restrict__ Wp, const float* __restrict__ bp,
    bf16* __restrict__ g)
{
    const int j = blockIdx.x;
    const int tid = threadIdx.x;
    float idxv = (j < N_SEQ) ? (float)j
                             : (j == N_SEQ ? 0.0f : (float)(j - 2 * N_SEQ));
    float h1 = idxv * Wp[tid] + bp[tid];
    float h2 = idxv * Wp[tid + 256] + bp[tid + 256];
    float ss = h1 * h1 + h2 * h2;
    #pragma unroll
    for (int off = 32; off > 0; off >>= 1) ss += __shfl_down(ss, off, 64);
    __shared__ float red[4];
    if ((tid & 63) == 0) red[tid >> 6] = ss;
    __syncthreads();
    float tot = red[0] + red[1] + red[2] + red[3];
    float scale = 1.0f / (sqrtf(tot) * 0.04419417382415922f + 1e-8f);
    g[(size_t)j * ED + tid]       = (bf16)fmaxf(h1 * scale, 0.0f);
    g[(size_t)j * ED + tid + 256] = (bf16)fmaxf(h2 * scale, 0.0f);
}

__global__ __launch_bounds__(256) void srms_relu_kernel(
    const float* __restrict__ in, bf16* __restrict__ out)
{
    const int row = blockIdx.x;
    const int tid = threadIdx.x;
    const float* p = in + (size_t)row * ED;

    float ss = 0.0f;
    for (int i = tid; i < ED; i += 256) { float x = p[i]; ss += x * x; }
    #pragma unroll
    for (int off = 32; off > 0; off >>= 1) ss += __shfl_down(ss, off, 64);
    __shared__ float red[4];
    if ((tid & 63) == 0) red[tid >> 6] = ss;
    __syncthreads();
    float tot = red[0] + red[1] + red[2] + red[3];
    float scale = 1.0f / (sqrtf(tot) * 0.04419417382415922f + 1e-8f);
    for (int i = tid; i < ED; i += 256)
        out[(size_t)row * ED + i] = (bf16)fmaxf(p[i] * scale, 0.0f);
}

// ---------------------------------------------------------------------------
// Radix-16 FFT, radix-4-factored butterflies, register tree twiddles.
// ---------------------------------------------------------------------------
#define FFT_LDS_SZ 4381
#define CC1 0.9238795325112867f
#define SS1 0.3826834323650898f
#define RR2 0.7071067811865476f

__device__ __forceinline__ int fpad(int i) { return i + (i >> 4) + 2 * (i >> 8); }

__device__ __forceinline__ float2 cmul(float2 a, float2 b) {
    return make_float2(a.x * b.x - a.y * b.y, a.x * b.y + a.y * b.x);
}
__device__ __forceinline__ float2 cadd(float2 a, float2 b) {
    return make_float2(a.x + b.x, a.y + b.y);
}
__device__ __forceinline__ float2 csub(float2 a, float2 b) {
    return make_float2(a.x - b.x, a.y - b.y);
}
__device__ __forceinline__ float2 cneg_i(float2 a) { return make_float2(a.y, -a.x); }
__device__ __forceinline__ float2 cpos_i(float2 a) { return make_float2(-a.y, a.x); }
__host__ __device__ constexpr int brev4(int t) {
    return ((t & 1) << 3) | ((t & 2) << 1) | ((t & 4) >> 1) | ((t & 8) >> 3);
}

template<bool HZ>
__device__ __forceinline__ void fft16_dif_r4(float2 x[16]) {
    const float2 W1 = make_float2( CC1, -SS1);
    const float2 W2 = make_float2( RR2, -RR2);
    const float2 W3 = make_float2( SS1, -CC1);
    const float2 W6 = make_float2(-RR2, -RR2);
    const float2 W9 = make_float2(-CC1,  SS1);
    #pragma unroll
    for (int n = 0; n < 4; ++n) {
        float2 A, B, C, D;
        if (HZ) { A = x[n]; C = x[n]; B = x[n + 4]; D = x[n + 4]; }
        else {
            A = cadd(x[n], x[n + 8]);  C = csub(x[n], x[n + 8]);
            B = cadd(x[n + 4], x[n + 12]); D = csub(x[n + 4], x[n + 12]);
        }
        float2 s = csub(A, B);
        float2 nid = cneg_i(D);
        float2 m = cadd(C, nid);
        float2 p = csub(C, nid);
        x[n] = cadd(A, B);
        if (n == 0)      { x[4] = s;            x[8]  = m;           x[12] = p; }
        else if (n == 1) { x[5] = cmul(s, W2);  x[9]  = cmul(m, W1); x[13] = cmul(p, W3); }
        else if (n == 2) { x[6] = cneg_i(s);    x[10] = cmul(m, W2); x[14] = cmul(p, W6); }
        else             { x[7] = cmul(s, W6);  x[11] = cmul(m, W3); x[15] = cmul(p, W9); }
    }
    #pragma unroll
    for (int q = 0; q < 16; q += 4) {
        float2 a = x[q], b = x[q + 1], c = x[q + 2], d = x[q + 3];
        float2 a1 = cadd(a, c), c1 = csub(a, c);
        float2 b1 = cadd(b, d), d1 = cneg_i(csub(b, d));
        x[q]     = cadd(a1, b1);
        x[q + 1] = csub(a1, b1);
        x[q + 2] = cadd(c1, d1);
        x[q + 3] = csub(c1, d1);
    }
}

template<bool HALF_OUT>
__device__ __forceinline__ void fft16_dit_inv_r4(float2 x[16]) {
    const float2 V1 = make_float2( CC1, SS1);
    const float2 V2 = make_float2( RR2, RR2);
    const float2 V3 = make_float2( SS1, CC1);
    const float2 V6 = make_float2(-RR2, RR2);
    #pragma unroll
    for (int q = 0; q < 16; q += 4) {
        float2 a = x[q], b = x[q + 1], c = x[q + 2], d = x[q + 3];
        float2 a1 = cadd(a, b), b1 = csub(a, b);
        float2 c1 = cadd(c, d), d1 = csub(c, d);
        float2 t = cpos_i(d1);
        x[q]     = cadd(a1, c1);
        x[q + 2] = csub(a1, c1);
        x[q + 1] = cadd(b1, t);
        x[q + 3] = csub(b1, t);
    }
    #pragma unroll
    for (int n = 0; n < 4; ++n) {
        float2 t1, t2;
        if (n == 0)      { t1 = x[4];             t2 = x[12]; }
        else if (n == 1) { t1 = cmul(x[5],  V2);  t2 = cmul(x[13], V2); }
        else if (n == 2) { t1 = cpos_i(x[6]);     t2 = cpos_i(x[14]); }
        else             { t1 = cmul(x[7],  V6);  t2 = cmul(x[15], V6); }
        float2 P = cadd(x[n], t1), Q = csub(x[n], t1);
        float2 R = cadd(x[n + 8], t2), S = csub(x[n + 8], t2);
        float2 t, u;
        if (n == 0)      { t = R;            u = S; }
        else if (n == 1) { t = cmul(R, V1);  u = cmul(S, V1); }
        else if (n == 2) { t = cmul(R, V2);  u = cmul(S, V2); }
        else             { t = cmul(R, V3);  u = cmul(S, V3); }
        float2 iu = cpos_i(u);
        x[n]     = cadd(P, t);
        x[n + 4] = cadd(Q, iu);
        if (!HALF_OUT) {
            x[n + 8]  = csub(P, t);
            x[n + 12] = csub(Q, iu);
        }
    }
}

__device__ __forceinline__ void stage_twiddle_tree(
    float2 v[16], int j, float rden, float sgn)
{
    float s, c;
    __sincosf(sgn * 6.283185307179586f * (float)j * rden, &s, &c);
    float2 w[16];
    w[1] = make_float2(c, s);
    w[2] = cmul(w[1], w[1]);
    w[3] = cmul(w[1], w[2]);
    w[4] = cmul(w[2], w[2]);
    w[5] = cmul(w[1], w[4]);
    w[6] = cmul(w[2], w[4]);
    w[7] = cmul(w[3], w[4]);
    w[8] = cmul(w[4], w[4]);
    #pragma unroll
    for (int t = 9; t < 16; ++t) w[t] = cmul(w[t - 8], w[8]);
    #pragma unroll
    for (int tau = 1; tau < 16; ++tau)
        v[brev4(tau)] = cmul(v[brev4(tau)], w[tau]);
}

template<bool HALF_ZERO>
__device__ void fft4096_fwd(float2* d, int tid)
{
    float2 v[16];
    {
        const int j = tid;
        if (HALF_ZERO) {
            #pragma unroll
            for (int t = 0; t < 8; ++t) v[t] = d[fpad(j + (t << 8))];
            fft16_dif_r4<true>(v);
        } else {
            #pragma unroll
            for (int t = 0; t < 16; ++t) v[t] = d[fpad(j + (t << 8))];
            fft16_dif_r4<false>(v);
        }
        stage_twiddle_tree(v, j, 1.0f / 4096.0f, -1.0f);
        #pragma unroll
        for (int p = 0; p < 16; ++p) d[fpad(j + (p << 8))] = v[p];
    }
    __syncthreads();
    {
        const int base = ((tid >> 4) << 8) + (tid & 15);
        #pragma unroll
        for (int t = 0; t < 16; ++t) v[t] = d[fpad(base + (t << 4))];
        fft16_dif_r4<false>(v);
        stage_twiddle_tree(v, tid & 15, 1.0f / 256.0f, -1.0f);
        #pragma unroll
        for (int p = 0; p < 16; ++p) d[fpad(base + (p << 4))] = v[p];
    }
    __syncthreads();
    {
        const int base = tid << 4;
        #pragma unroll
        for (int t = 0; t < 16; ++t) v[t] = d[fpad(base + t)];
        fft16_dif_r4<false>(v);
        #pragma unroll
        for (int p = 0; p < 16; ++p) d[fpad(base + p)] = v[p];
    }
    __syncthreads();
}

// ---------------------------------------------------------------------------
__global__ __launch_bounds__(256) void fft_a_kernel(
    const float* __restrict__ a_t, float2* __restrict__ Wspec)
{
    __shared__ float2 data[FFT_LDS_SZ];
    const int tid = threadIdx.x;
    const int h = blockIdx.x / 96, dp = blockIdx.x % 96;

    const float* r0 = a_t + ((size_t)(h * HD + 2 * dp)) * M_FFT;
    const float* r1 = r0 + M_FFT;

    for (int j = tid; j < 4096; j += 256) data[fpad(j)] = make_float2(r0[j], r1[j]);
    __syncthreads();
    fft4096_fwd<false>(data, tid);

    float2* outrow = Wspec + (size_t)blockIdx.x * 4096;
    for (int j = tid; j < 4096; j += 256) outrow[j] = data[fpad(j)];
}

// ---------------------------------------------------------------------------
__global__ __launch_bounds__(256) void fft_conv_kernel(
    const bf16* __restrict__ v_t, const float2* __restrict__ Wspec,
    const bf16* __restrict__ u_t, bf16* __restrict__ gated_t)
{
    __shared__ float2 data[FFT_LDS_SZ];
    const int tid = threadIdx.x;
    const int bx = blockIdx.x;
    const int b  = bx / 768;
    const int r  = bx % 768;
    const int h  = r / 96, dp = r % 96;
    const int ch = h * HD + 2 * dp;

    const bf16* z0 = v_t + ((size_t)(b * D1 + ch)) * N_SEQ;
    const bf16* z1 = z0 + N_SEQ;

    {
        const int s = tid * 8;
        bf16x8 a0 = *(const bf16x8*)(z0 + s);
        bf16x8 a1 = *(const bf16x8*)(z1 + s);
        #pragma unroll
        for (int i = 0; i < 8; ++i)
            data[fpad(s + i)] = make_float2((float)a0[i], (float)a1[i]);
    }
    __syncthreads();

    fft4096_fwd<true>(data, tid);

    // fused per-bin pointwise + inverse stage 1 (owned positions base..base+15)
    const float2* Wrow = Wspec + (size_t)r * 4096;
    float2 v[16];
    {
        const int base = tid << 4;
        #pragma unroll
        for (int i = 0; i < 16; ++i) {
            const int p  = base + i;
            const int k  = __brev((unsigned)p) >> 20;
            const int km = (4096 - k) & 4095;
            const int p2 = __brev((unsigned)km) >> 20;
            float2 Zk = data[fpad(p)];
            float2 Zm = data[fpad(p2)];
            float2 Wk = Wrow[p];
            float2 Wm = Wrow[p2];
            float2 V0 = make_float2(0.5f * (Zk.x + Zm.x), 0.5f * (Zk.y - Zm.y));
            float2 V1 = make_float2(0.5f * (Zk.y + Zm.y), 0.5f * (Zm.x - Zk.x));
            float2 A0 = make_float2(0.5f * (Wk.x + Wm.x), 0.5f * (Wk.y - Wm.y));
            float2 A1 = make_float2(0.5f * (Wk.y + Wm.y), 0.5f * (Wm.x - Wk.x));
            float2 P = cmul(V0, A0), Q = cmul(V1, A1);
            v[i] = make_float2(P.x - Q.y, P.y + Q.x);   // Y = P + iQ
        }
        __syncthreads();              // all pointwise reads complete
        fft16_dit_inv_r4<false>(v);   // undo fwd stage 3
        #pragma unroll
        for (int i = 0; i < 16; ++i) data[fpad(base + i)] = v[i];
    }
    __syncthreads();
    {   // inverse stage 2
        const int base = ((tid >> 4) << 8) + (tid & 15);
        #pragma unroll
        for (int p = 0; p < 16; ++p) v[p] = data[fpad(base + (p << 4))];
        stage_twiddle_tree(v, tid & 15, 1.0f / 256.0f, 1.0f);
        fft16_dit_inv_r4<false>(v);
        #pragma unroll
        for (int t = 0; t < 16; ++t) data[fpad(base + (t << 4))] = v[t];
    }
    __syncthreads();
    {   // inverse stage 3, lower half only
        const int j = tid;
        #pragma unroll
        for (int p = 0; p < 16; ++p) v[p] = data[fpad(j + (p << 8))];
        stage_twiddle_tree(v, j, 1.0f / 4096.0f, 1.0f);
        fft16_dit_inv_r4<true>(v);
        #pragma unroll
        for (int t = 0; t < 8; ++t) data[fpad(j + (t << 8))] = v[t];
    }
    __syncthreads();

    const float inv_m = 1.0f / 4096.0f;
    const bf16* u0 = u_t + ((size_t)(b * D1 + ch)) * N_SEQ;
    const bf16* u1 = u0 + N_SEQ;
    bf16* g0 = gated_t + ((size_t)(b * D1 + ch)) * N_SEQ;
    bf16* g1 = g0 + N_SEQ;
    {
        const int t = tid * 8;
        bf16x8 ua = *(const bf16x8*)(u0 + t);
        bf16x8 ub = *(const bf16x8*)(u1 + t);
        bf16x8 oa, ob;
        #pragma unroll
        for (int i = 0; i < 8; ++i) {
            float2 y = data[fpad(t + i)];
            oa[i] = (bf16)(y.x * inv_m * (float)ua[i]);
            ob[i] = (bf16)(y.y * inv_m * (float)ub[i]);
        }
        *(bf16x8*)(g0 + t) = oa;
        *(bf16x8*)(g1 + t) = ob;
    }
}

// ---------------------------------------------------------------------------
__global__ __launch_bounds__(256) void transpose_cs_kernel(
    const bf16* __restrict__ in, bf16* __restrict__ outp)
{
    __shared__ bf16 tile[64 * 68];
    const int c0 = blockIdx.x * 64;
    const int m0 = blockIdx.y * 64;
    const int b  = m0 >> 11;
    const int s0 = m0 & 2047;
    const int tid = threadIdx.x;
    const int cl = tid >> 4;
    const int sc = (tid & 15) * 4;
    #pragma unroll
    for (int p = 0; p < 4; ++p) {
        int c = p * 16 + cl;
        bf16x4 v = *(const bf16x4*)&in[((size_t)(b * D1 + c0 + c)) * N_SEQ + s0 + sc];
        *(bf16x4*)&tile[c * 68 + sc] = v;
    }
    __syncthreads();
    const int sl = tid >> 4;
    const int cc = (tid & 15) * 4;
    #pragma unroll
    for (int p = 0; p < 4; ++p) {
        int s = p * 16 + sl;
        bf16x4 o;
        #pragma unroll
        for (int j = 0; j < 4; ++j) o[j] = tile[(cc + j) * 68 + s];
        *(bf16x4*)&outp[((size_t)(m0 + s)) * D1 + c0 + cc] = o;
    }
}

// ---------------------------------------------------------------------------
extern "C" void kernel_launch(void* const* d_in, const int* in_sizes, int n_in,
                              void* d_out, int out_size, void* d_ws, size_t ws_size,
                              hipStream_t stream)
{
    const float* x  = (const float*)d_in[0];
    const float* Wu = (const float*)d_in[1];
    const float* bu = (const float*)d_in[2];
    const float* Wv = (const float*)d_in[3];
    const float* bv = (const float*)d_in[4];
    const float* Wo = (const float*)d_in[5];
    const float* bo = (const float*)d_in[6];
    const float* Wp = (const float*)d_in[7];
    const float* bp = (const float*)d_in[8];
    const float* Wl = (const float*)d_in[9];
    const float* bl = (const float*)d_in[10];
    const float* Wr = (const float*)d_in[11];
    const float* br = (const float*)d_in[12];
    float* out = (float*)d_out;

    float* ws      = (float*)d_ws;
    float* a_t     = ws;                       // 1536*4096 fp32
    float* Wspec   = a_t   + 6291456;          // 768 x 4096 float2
    float* h0      = Wspec + 6291456;          // 4096*512 fp32
    bf16*  bfws    = (bf16*)(h0 + 2097152);
    bf16*  x_bf    = bfws;                     // 8192*512
    bf16*  w_bf    = x_bf    + 4194304;        // 5 x 786432: Wu,Wv,Wo,Wl,Wr
    bf16*  Wuv_bf  = w_bf;                     // stacked [Wu;Wv] 3072 x 512
    bf16*  Wo_bf   = w_bf    + 2 * 786432;
    bf16*  Wl_bf   = Wo_bf   + 786432;
    bf16*  Wr_bf   = Wl_bf   + 786432;
    bf16*  g_bf    = Wr_bf   + 786432;         // 4096*512
    bf16*  u_t     = g_bf    + 2097152;        // 8192*1536 [b][c][s]
    bf16*  v_t     = u_t     + 12582912;       // 8192*1536 [b][c][s]
    bf16*  gated_t = v_t     + 12582912;       // 8192*1536 [b][c][s]
    bf16*  gated   = gated_t + 12582912;       // 8192*1536 [m][c]

    dim3 blk(256);

    f2b_all_kernel<<<4096 + 5 * 768, blk, 0, stream>>>(
        x, Wu, Wv, Wo, Wl, Wr, x_bf, w_bf);

    gemm_bf16<MODE_SILU_UV, bf16><<<dim3(24, 64), blk, 0, stream>>>(
        x_bf, Wuv_bf, bu, bv, u_t, v_t, 8192, 2 * D1, ED);

    rpe_in_srms_kernel<<<4096, blk, 0, stream>>>(Wp, bp, g_bf);
    for (int i = 0; i < 3; ++i) {
        gemm_bf16<MODE_PLAIN, float><<<dim3(4, 32), blk, 0, stream>>>(
            g_bf, Wl_bf + (size_t)i * ED * ED, bl + (size_t)i * ED, nullptr,
            h0, nullptr, 4096, ED, ED);
        srms_relu_kernel<<<4096, blk, 0, stream>>>(h0, g_bf);
    }
    gemm_bf16<MODE_AT, float><<<dim3(12, 32), blk, 0, stream>>>(
        g_bf, Wr_bf, br, nullptr, a_t, nullptr, 4096, D1, ED);

    fft_a_kernel<<<768, blk, 0, stream>>>(a_t, (float2*)Wspec);
    fft_conv_kernel<<<3072, blk, 0, stream>>>(
        v_t, (const float2*)Wspec, u_t, gated_t);

    transpose_cs_kernel<<<dim3(24, 128), blk, 0, stream>>>(gated_t, gated);

    gemm_bf16<MODE_PLAIN, float><<<dim3(4, 64), blk, 0, stream>>>(
        gated, Wo_bf, bo, nullptr, out, nullptr, 8192, ED, D1);
}

// Round 8
// 358.805 us; speedup vs baseline: 3.3113x; 1.0187x over previous
//
#include <hip/hip_runtime.h>

#define N_SEQ 2048
#define M_FFT 4096
#define D1    1536
#define NH    8
#define HD    192
#define ED    512

typedef __bf16 bf16;
typedef __bf16 bf16x4 __attribute__((ext_vector_type(4)));
typedef __bf16 bf16x8 __attribute__((ext_vector_type(8)));
typedef float  floatx4 __attribute__((ext_vector_type(4)));
typedef float  cx __attribute__((ext_vector_type(2)));   // complex as packed fp32

enum { MODE_PLAIN = 0, MODE_SILU_UV = 1, MODE_AT = 3, MODE_RPE = 4 };

__device__ __forceinline__ void gload16(const void* g, void* l) {
    __builtin_amdgcn_global_load_lds(
        (const __attribute__((address_space(1))) void*)g,
        (__attribute__((address_space(3))) void*)l, 16, 0, 0);
}

// ---------------------------------------------------------------------------
// bf16 MFMA GEMM (m97 structure): C = epilogue(A(MxK) @ Bw(NcxK)^T + bias)
// MODE_RPE: val = acc*scale_prev[row] + bias; atomic row sum-sq; relu; bf16.
// MODE_AT : val = acc*scale_prev[row] + bias; fp32 transposed store.
// ---------------------------------------------------------------------------
template<int MODE, typename OutT>
__global__ __launch_bounds__(256) void gemm_bf16(
    const bf16* __restrict__ A, const bf16* __restrict__ Bw,
    const float* __restrict__ bias, const float* __restrict__ bias2,
    OutT* __restrict__ C, OutT* __restrict__ C2,
    int M, int Nc, int K,
    const float* __restrict__ scale_in, float* __restrict__ sumsq_out)
{
    __shared__ __align__(16) bf16 As[128 * 32];
    __shared__ __align__(16) bf16 Bs[128 * 32];

    const int tid  = threadIdx.x;
    const int row0 = blockIdx.y * 128;
    const int col0 = blockIdx.x * 128;
    const int wid  = tid >> 6;
    const int lane = tid & 63;
    const int lm   = lane & 15;
    const int lk   = lane >> 4;
    const int wm   = wid >> 1;
    const int wn   = wid & 1;
    const int ldrow  = tid >> 2;
    const int ldcol8 = (tid & 3) * 8;

    floatx4 acc[4][4] = {};

    const bf16* Ag = A  + ((size_t)(row0 + ldrow)) * K + ldcol8;
    const bf16* Bg = Bw + ((size_t)(col0 + ldrow)) * K + ldcol8;
    bf16* AsW = As + (wid * 16) * 32;
    bf16* BsW = Bs + (wid * 16) * 32;

    for (int k0 = 0; k0 < K; k0 += 32) {
        gload16(Ag + k0, AsW);
        gload16(Ag + (size_t)64 * K + k0, AsW + 64 * 32);
        gload16(Bg + k0, BsW);
        gload16(Bg + (size_t)64 * K + k0, BsW + 64 * 32);
        __syncthreads();

        bf16x8 af[4], bfr[4];
        #pragma unroll
        for (int mi = 0; mi < 4; ++mi)
            af[mi] = *(const bf16x8*)&As[(wm * 64 + mi * 16 + lm) * 32 + lk * 8];
        #pragma unroll
        for (int nj = 0; nj < 4; ++nj)
            bfr[nj] = *(const bf16x8*)&Bs[(wn * 64 + nj * 16 + lm) * 32 + lk * 8];
        #pragma unroll
        for (int mi = 0; mi < 4; ++mi)
            #pragma unroll
            for (int nj = 0; nj < 4; ++nj)
                acc[mi][nj] = __builtin_amdgcn_mfma_f32_16x16x32_bf16(
                    af[mi], bfr[nj], acc[mi][nj], 0, 0, 0);
        __syncthreads();
    }

    const float* bs = bias;
    OutT* dst = C;
    int cadj = 0;
    if (MODE == MODE_SILU_UV && col0 >= D1) { bs = bias2; dst = C2; cadj = D1; }

    float bcol[4];
    #pragma unroll
    for (int nj = 0; nj < 4; ++nj)
        bcol[nj] = bs[col0 - cadj + wn * 64 + nj * 16 + lm];

    if (MODE == MODE_RPE) {
        #pragma unroll
        for (int mi = 0; mi < 4; ++mi) {
            #pragma unroll
            for (int r = 0; r < 4; ++r) {
                const int row = row0 + wm * 64 + mi * 16 + lk * 4 + r;
                float sc = 1.0f;
                if (scale_in)
                    sc = 1.0f / (sqrtf(scale_in[row]) * 0.04419417382415922f + 1e-8f);
                float ssq = 0.0f;
                #pragma unroll
                for (int nj = 0; nj < 4; ++nj) {
                    const int col = col0 + wn * 64 + nj * 16 + lm;
                    float val = acc[mi][nj][r] * sc + bcol[nj];
                    ssq += val * val;
                    ((bf16*)C)[(size_t)row * Nc + col] = (bf16)fmaxf(val, 0.0f);
                }
                ssq += __shfl_xor(ssq, 1, 64);
                ssq += __shfl_xor(ssq, 2, 64);
                ssq += __shfl_xor(ssq, 4, 64);
                ssq += __shfl_xor(ssq, 8, 64);
                if (lm == 0) atomicAdd(&sumsq_out[row], ssq);
            }
        }
        return;
    }

    #pragma unroll
    for (int mi = 0; mi < 4; ++mi) {
        const int rbase = row0 + wm * 64 + mi * 16 + lk * 4;
        float sc[4];
        #pragma unroll
        for (int r = 0; r < 4; ++r) {
            sc[r] = 1.0f;
            if (MODE == MODE_AT && scale_in)
                sc[r] = 1.0f / (sqrtf(scale_in[rbase + r]) * 0.04419417382415922f + 1e-8f);
        }
        #pragma unroll
        for (int nj = 0; nj < 4; ++nj) {
            const int col = col0 - cadj + wn * 64 + nj * 16 + lm;
            float vals[4];
            #pragma unroll
            for (int r = 0; r < 4; ++r) {
                float val = acc[mi][nj][r] * sc[r] + bcol[nj];
                if (MODE == MODE_SILU_UV)
                    val = val / (1.0f + __expf(-val));
                vals[r] = val;
            }
            if (MODE == MODE_SILU_UV) {
                int b = rbase >> 11, s = rbase & 2047;
                bf16x4 o;
                #pragma unroll
                for (int r = 0; r < 4; ++r) o[r] = (bf16)vals[r];
                *(bf16x4*)&((bf16*)dst)[((size_t)(b * D1 + col)) * N_SEQ + s] = o;
            } else if (MODE == MODE_AT) {
                float4 o = make_float4(vals[0], vals[1], vals[2], vals[3]);
                *(float4*)&((float*)C)[(size_t)col * M + rbase] = o;
            } else {
                #pragma unroll
                for (int r = 0; r < 4; ++r)
                    C[(size_t)(rbase + r) * Nc + col] = (OutT)vals[r];
            }
        }
    }
}

// ---------------------------------------------------------------------------
// mega-prologue: x convert (4096 blk) + 5 weight converts (3840 blk) +
// sumsq zero (12 blk) + RPE input layer w/ srms (4096 blk)
// ---------------------------------------------------------------------------
__global__ __launch_bounds__(256) void f2b_all_kernel(
    const float* __restrict__ x,  const float* __restrict__ s0,
    const float* __restrict__ s1, const float* __restrict__ s2,
    const float* __restrict__ s3, const float* __restrict__ s4,
    const float* __restrict__ Wp, const float* __restrict__ bp,
    bf16* __restrict__ x_bf, bf16* __restrict__ w_bf,
    float* __restrict__ sumsq, bf16* __restrict__ g0)
{
    const int bid = blockIdx.x;
    const int tid = threadIdx.x;
    __shared__ float red[4];

    if (bid < 7936) {
        const float* src;
        bf16* dst;
        size_t off;
        if (bid < 4096) {
            src = x; dst = x_bf; off = (size_t)bid * 1024;
        } else {
            int t = bid - 4096;
            int seg = t / 768;
            src = seg == 0 ? s0 : seg == 1 ? s1 : seg == 2 ? s2
                : seg == 3 ? s3 : s4;
            dst = w_bf + (size_t)seg * 786432;
            off = (size_t)(t % 768) * 1024;
        }
        size_t i = off + (size_t)tid * 4;
        float4 f = *(const float4*)(src + i);
        union { bf16 h[4]; short4 s; } u4;
        u4.h[0] = (bf16)f.x; u4.h[1] = (bf16)f.y;
        u4.h[2] = (bf16)f.z; u4.h[3] = (bf16)f.w;
        *(short4*)(dst + i) = u4.s;
    } else if (bid < 7948) {
        size_t i = (size_t)(bid - 7936) * 1024 + (size_t)tid * 4;
        *(float4*)(sumsq + i) = make_float4(0.f, 0.f, 0.f, 0.f);
    } else {
        const int j = bid - 7948;
        float idxv = (j < N_SEQ) ? (float)j
                                 : (j == N_SEQ ? 0.0f : (float)(j - 2 * N_SEQ));
        float h1 = idxv * Wp[tid] + bp[tid];
        float h2 = idxv * Wp[tid + 256] + bp[tid + 256];
        float ss = h1 * h1 + h2 * h2;
        #pragma unroll
        for (int off = 32; off > 0; off >>= 1) ss += __shfl_down(ss, off, 64);
        if ((tid & 63) == 0) red[tid >> 6] = ss;
        __syncthreads();
        float tot = red[0] + red[1] + red[2] + red[3];
        float scale = 1.0f / (sqrtf(tot) * 0.04419417382415922f + 1e-8f);
        g0[(size_t)j * ED + tid]       = (bf16)fmaxf(h1 * scale, 0.0f);
        g0[(size_t)j * ED + tid + 256] = (bf16)fmaxf(h2 * scale, 0.0f);
    }
}

// ---------------------------------------------------------------------------
// Radix-16 FFT, radix-4 butterflies, packed-fp32 complex (v_pk_* ops).
// ---------------------------------------------------------------------------
#define FFT_LDS_SZ 4381
#define CC1 0.9238795325112867f
#define SS1 0.3826834323650898f
#define RR2 0.7071067811865476f

__device__ __forceinline__ int fpad(int i) { return i + (i >> 4) + 2 * (i >> 8); }

__device__ __forceinline__ cx mkcx(float a, float b) { cx r; r.x = a; r.y = b; return r; }
__device__ __forceinline__ cx cmul(cx a, cx b) {
    cx br = mkcx(-b.y, b.x);
    return a.xx * b + a.yy * br;
}
__device__ __forceinline__ cx cneg_i(cx a) { return mkcx(a.y, -a.x); }   // a * (-i)
__device__ __forceinline__ cx cpos_i(cx a) { return mkcx(-a.y, a.x); }   // a * (+i)
__host__ __device__ constexpr int brev4(int t) {
    return ((t & 1) << 3) | ((t & 2) << 1) | ((t & 4) >> 1) | ((t & 8) >> 3);
}

template<bool HZ>
__device__ __forceinline__ void fft16_dif_r4(cx x[16]) {
    const cx W1 = mkcx( CC1, -SS1);
    const cx W2 = mkcx( RR2, -RR2);
    const cx W3 = mkcx( SS1, -CC1);
    const cx W6 = mkcx(-RR2, -RR2);
    const cx W9 = mkcx(-CC1,  SS1);
    #pragma unroll
    for (int n = 0; n < 4; ++n) {
        cx A, B, C, D;
        if (HZ) { A = x[n]; C = x[n]; B = x[n + 4]; D = x[n + 4]; }
        else {
            A = x[n] + x[n + 8];      C = x[n] - x[n + 8];
            B = x[n + 4] + x[n + 12]; D = x[n + 4] - x[n + 12];
        }
        cx s = A - B;
        cx nid = cneg_i(D);
        cx m = C + nid;
        cx p = C - nid;
        x[n] = A + B;
        if (n == 0)      { x[4] = s;            x[8]  = m;           x[12] = p; }
        else if (n == 1) { x[5] = cmul(s, W2);  x[9]  = cmul(m, W1); x[13] = cmul(p, W3); }
        else if (n == 2) { x[6] = cneg_i(s);    x[10] = cmul(m, W2); x[14] = cmul(p, W6); }
        else             { x[7] = cmul(s, W6);  x[11] = cmul(m, W3); x[15] = cmul(p, W9); }
    }
    #pragma unroll
    for (int q = 0; q < 16; q += 4) {
        cx a = x[q], b = x[q + 1], c = x[q + 2], d = x[q + 3];
        cx a1 = a + c, c1 = a - c;
        cx b1 = b + d, d1 = cneg_i(b - d);
        x[q]     = a1 + b1;
        x[q + 1] = a1 - b1;
        x[q + 2] = c1 + d1;
        x[q + 3] = c1 - d1;
    }
}

template<bool HALF_OUT>
__device__ __forceinline__ void fft16_dit_inv_r4(cx x[16]) {
    const cx V1 = mkcx( CC1, SS1);
    const cx V2 = mkcx( RR2, RR2);
    const cx V3 = mkcx( SS1, CC1);
    const cx V6 = mkcx(-RR2, RR2);
    #pragma unroll
    for (int q = 0; q < 16; q += 4) {
        cx a = x[q], b = x[q + 1], c = x[q + 2], d = x[q + 3];
        cx a1 = a + b, b1 = a - b;
        cx c1 = c + d, d1 = c - d;
        cx t = cpos_i(d1);
        x[q]     = a1 + c1;
        x[q + 2] = a1 - c1;
        x[q + 1] = b1 + t;
        x[q + 3] = b1 - t;
    }
    #pragma unroll
    for (int n = 0; n < 4; ++n) {
        cx t1, t2;
        if (n == 0)      { t1 = x[4];             t2 = x[12]; }
        else if (n == 1) { t1 = cmul(x[5],  V2);  t2 = cmul(x[13], V2); }
        else if (n == 2) { t1 = cpos_i(x[6]);     t2 = cpos_i(x[14]); }
        else             { t1 = cmul(x[7],  V6);  t2 = cmul(x[15], V6); }
        cx P = x[n] + t1, Q = x[n] - t1;
        cx R = x[n + 8] + t2, S = x[n + 8] - t2;
        cx t, u;
        if (n == 0)      { t = R;            u = S; }
        else if (n == 1) { t = cmul(R, V1);  u = cmul(S, V1); }
        else if (n == 2) { t = cmul(R, V2);  u = cmul(S, V2); }
        else             { t = cmul(R, V3);  u = cmul(S, V3); }
        cx iu = cpos_i(u);
        x[n]     = P + t;
        x[n + 4] = Q + iu;
        if (!HALF_OUT) {
            x[n + 8]  = P - t;
            x[n + 12] = Q - iu;
        }
    }
}

__device__ __forceinline__ void stage_twiddle_tree(
    cx v[16], int j, float rden, float sgn)
{
    float s, c;
    __sincosf(sgn * 6.283185307179586f * (float)j * rden, &s, &c);
    cx w[16];
    w[1] = mkcx(c, s);
    w[2] = cmul(w[1], w[1]);
    w[3] = cmul(w[1], w[2]);
    w[4] = cmul(w[2], w[2]);
    w[5] = cmul(w[1], w[4]);
    w[6] = cmul(w[2], w[4]);
    w[7] = cmul(w[3], w[4]);
    w[8] = cmul(w[4], w[4]);
    #pragma unroll
    for (int t = 9; t < 16; ++t) w[t] = cmul(w[t - 8], w[8]);
    #pragma unroll
    for (int tau = 1; tau < 16; ++tau)
        v[brev4(tau)] = cmul(v[brev4(tau)], w[tau]);
}

template<bool HALF_ZERO>
__device__ void fft4096_fwd(cx* d, int tid)
{
    cx v[16];
    {
        const int j = tid;
        if (HALF_ZERO) {
            #pragma unroll
            for (int t = 0; t < 8; ++t) v[t] = d[fpad(j + (t << 8))];
            fft16_dif_r4<true>(v);
        } else {
            #pragma unroll
            for (int t = 0; t < 16; ++t) v[t] = d[fpad(j + (t << 8))];
            fft16_dif_r4<false>(v);
        }
        stage_twiddle_tree(v, j, 1.0f / 4096.0f, -1.0f);
        #pragma unroll
        for (int p = 0; p < 16; ++p) d[fpad(j + (p << 8))] = v[p];
    }
    __syncthreads();
    {
        const int base = ((tid >> 4) << 8) + (tid & 15);
        #pragma unroll
        for (int t = 0; t < 16; ++t) v[t] = d[fpad(base + (t << 4))];
        fft16_dif_r4<false>(v);
        stage_twiddle_tree(v, tid & 15, 1.0f / 256.0f, -1.0f);
        #pragma unroll
        for (int p = 0; p < 16; ++p) d[fpad(base + (p << 4))] = v[p];
    }
    __syncthreads();
    {
        const int base = tid << 4;
        #pragma unroll
        for (int t = 0; t < 16; ++t) v[t] = d[fpad(base + t)];
        fft16_dif_r4<false>(v);
        #pragma unroll
        for (int p = 0; p < 16; ++p) d[fpad(base + p)] = v[p];
    }
    __syncthreads();
}

// ---------------------------------------------------------------------------
__global__ __launch_bounds__(256) void fft_a_kernel(
    const float* __restrict__ a_t, cx* __restrict__ Wspec)
{
    __shared__ cx data[FFT_LDS_SZ];
    const int tid = threadIdx.x;
    const int h = blockIdx.x / 96, dp = blockIdx.x % 96;

    const float* r0 = a_t + ((size_t)(h * HD + 2 * dp)) * M_FFT;
    const float* r1 = r0 + M_FFT;

    for (int j = tid; j < 4096; j += 256) data[fpad(j)] = mkcx(r0[j], r1[j]);
    __syncthreads();
    fft4096_fwd<false>(data, tid);

    cx* outrow = Wspec + (size_t)blockIdx.x * 4096;
    for (int j = tid; j < 4096; j += 256) outrow[j] = data[fpad(j)];
}

// ---------------------------------------------------------------------------
__global__ __launch_bounds__(256) void fft_conv_kernel(
    const bf16* __restrict__ v_t, const cx* __restrict__ Wspec,
    const bf16* __restrict__ u_t, bf16* __restrict__ gated_t)
{
    __shared__ cx data[FFT_LDS_SZ];
    const int tid = threadIdx.x;
    const int bx = blockIdx.x;
    const int b  = bx / 768;
    const int r  = bx % 768;
    const int h  = r / 96, dp = r % 96;
    const int ch = h * HD + 2 * dp;

    const bf16* z0 = v_t + ((size_t)(b * D1 + ch)) * N_SEQ;
    const bf16* z1 = z0 + N_SEQ;

    {
        const int s = tid * 8;
        bf16x8 a0 = *(const bf16x8*)(z0 + s);
        bf16x8 a1 = *(const bf16x8*)(z1 + s);
        #pragma unroll
        for (int i = 0; i < 8; ++i)
            data[fpad(s + i)] = mkcx((float)a0[i], (float)a1[i]);
    }
    __syncthreads();

    fft4096_fwd<true>(data, tid);

    // fused per-bin pointwise + inverse stage 1
    const cx* Wrow = Wspec + (size_t)r * 4096;
    cx v[16];
    {
        const int base = tid << 4;
        #pragma unroll
        for (int i = 0; i < 16; ++i) {
            const int p  = base + i;
            const int k  = __brev((unsigned)p) >> 20;
            const int km = (4096 - k) & 4095;
            const int p2 = __brev((unsigned)km) >> 20;
            cx Zk = data[fpad(p)];
            cx Zm = data[fpad(p2)];
            cx Wk = Wrow[p];
            cx Wm = Wrow[p2];
            cx V0 = 0.5f * (Zk + mkcx(Zm.x, -Zm.y));
            cx V1 = 0.5f * (mkcx(Zk.y, -Zk.x) + mkcx(Zm.y, Zm.x));
            cx A0 = 0.5f * (Wk + mkcx(Wm.x, -Wm.y));
            cx A1 = 0.5f * (mkcx(Wk.y, -Wk.x) + mkcx(Wm.y, Wm.x));
            cx P = cmul(V0, A0), Q = cmul(V1, A1);
            v[i] = P + cpos_i(Q);              // Y = P + iQ
        }
        __syncthreads();
        fft16_dit_inv_r4<false>(v);
        #pragma unroll
        for (int i = 0; i < 16; ++i) data[fpad(base + i)] = v[i];
    }
    __syncthreads();
    {   // inverse stage 2
        const int base = ((tid >> 4) << 8) + (tid & 15);
        #pragma unroll
        for (int p = 0; p < 16; ++p) v[p] = data[fpad(base + (p << 4))];
        stage_twiddle_tree(v, tid & 15, 1.0f / 256.0f, 1.0f);
        fft16_dit_inv_r4<false>(v);
        #pragma unroll
        for (int t = 0; t < 16; ++t) data[fpad(base + (t << 4))] = v[t];
    }
    __syncthreads();
    {   // inverse stage 3, lower half only
        const int j = tid;
        #pragma unroll
        for (int p = 0; p < 16; ++p) v[p] = data[fpad(j + (p << 8))];
        stage_twiddle_tree(v, j, 1.0f / 4096.0f, 1.0f);
        fft16_dit_inv_r4<true>(v);
        #pragma unroll
        for (int t = 0; t < 8; ++t) data[fpad(j + (t << 8))] = v[t];
    }
    __syncthreads();

    const float inv_m = 1.0f / 4096.0f;
    const bf16* u0 = u_t + ((size_t)(b * D1 + ch)) * N_SEQ;
    const bf16* u1 = u0 + N_SEQ;
    bf16* g0 = gated_t + ((size_t)(b * D1 + ch)) * N_SEQ;
    bf16* g1 = g0 + N_SEQ;
    {
        const int t = tid * 8;
        bf16x8 ua = *(const bf16x8*)(u0 + t);
        bf16x8 ub = *(const bf16x8*)(u1 + t);
        bf16x8 oa, ob;
        #pragma unroll
        for (int i = 0; i < 8; ++i) {
            cx y = data[fpad(t + i)];
            oa[i] = (bf16)(y.x * inv_m * (float)ua[i]);
            ob[i] = (bf16)(y.y * inv_m * (float)ub[i]);
        }
        *(bf16x8*)(g0 + t) = oa;
        *(bf16x8*)(g1 + t) = ob;
    }
}

// ---------------------------------------------------------------------------
__global__ __launch_bounds__(256) void transpose_cs_kernel(
    const bf16* __restrict__ in, bf16* __restrict__ outp)
{
    __shared__ bf16 tile[64 * 68];
    const int c0 = blockIdx.x * 64;
    const int m0 = blockIdx.y * 64;
    const int b  = m0 >> 11;
    const int s0 = m0 & 2047;
    const int tid = threadIdx.x;
    const int cl = tid >> 4;
    const int sc = (tid & 15) * 4;
    #pragma unroll
    for (int p = 0; p < 4; ++p) {
        int c = p * 16 + cl;
        bf16x4 v = *(const bf16x4*)&in[((size_t)(b * D1 + c0 + c)) * N_SEQ + s0 + sc];
        *(bf16x4*)&tile[c * 68 + sc] = v;
    }
    __syncthreads();
    const int sl = tid >> 4;
    const int cc = (tid & 15) * 4;
    #pragma unroll
    for (int p = 0; p < 4; ++p) {
        int s = p * 16 + sl;
        bf16x4 o;
        #pragma unroll
        for (int j = 0; j < 4; ++j) o[j] = tile[(cc + j) * 68 + s];
        *(bf16x4*)&outp[((size_t)(m0 + s)) * D1 + c0 + cc] = o;
    }
}

// ---------------------------------------------------------------------------
extern "C" void kernel_launch(void* const* d_in, const int* in_sizes, int n_in,
                              void* d_out, int out_size, void* d_ws, size_t ws_size,
                              hipStream_t stream)
{
    const float* x  = (const float*)d_in[0];
    const float* Wu = (const float*)d_in[1];
    const float* bu = (const float*)d_in[2];
    const float* Wv = (const float*)d_in[3];
    const float* bv = (const float*)d_in[4];
    const float* Wo = (const float*)d_in[5];
    const float* bo = (const float*)d_in[6];
    const float* Wp = (const float*)d_in[7];
    const float* bp = (const float*)d_in[8];
    const float* Wl = (const float*)d_in[9];
    const float* bl = (const float*)d_in[10];
    const float* Wr = (const float*)d_in[11];
    const float* br = (const float*)d_in[12];
    float* out = (float*)d_out;

    float* ws      = (float*)d_ws;
    float* a_t     = ws;                       // 1536*4096 fp32
    float* Wspec   = a_t   + 6291456;          // 768 x 4096 cx
    float* sumsq   = Wspec + 6291456;          // 3 x 4096 fp32
    bf16*  bfws    = (bf16*)(sumsq + 12288);
    bf16*  x_bf    = bfws;                     // 8192*512
    bf16*  w_bf    = x_bf    + 4194304;        // 5 x 786432: Wu,Wv,Wo,Wl,Wr
    bf16*  Wuv_bf  = w_bf;                     // stacked [Wu;Wv] 3072 x 512
    bf16*  Wo_bf   = w_bf    + 2 * 786432;
    bf16*  Wl_bf   = Wo_bf   + 786432;
    bf16*  Wr_bf   = Wl_bf   + 786432;
    bf16*  gA      = Wr_bf   + 786432;         // 4096*512
    bf16*  gB      = gA      + 2097152;        // 4096*512
    bf16*  u_t     = gB      + 2097152;        // 8192*1536 [b][c][s]
    bf16*  v_t     = u_t     + 12582912;       // 8192*1536 [b][c][s]
    bf16*  gated_t = v_t     + 12582912;       // 8192*1536 [b][c][s]
    bf16*  gated   = gated_t + 12582912;       // 8192*1536 [m][c]

    dim3 blk(256);

    // x/w converts + sumsq zero + rpe input layer
    f2b_all_kernel<<<4096 + 5 * 768 + 12 + 4096, blk, 0, stream>>>(
        x, Wu, Wv, Wo, Wl, Wr, Wp, bp, x_bf, w_bf, sumsq, gA);

    gemm_bf16<MODE_SILU_UV, bf16><<<dim3(24, 64), blk, 0, stream>>>(
        x_bf, Wuv_bf, bu, bv, u_t, v_t, 8192, 2 * D1, ED, nullptr, nullptr);

    // RPE MLP: srms folded into GEMM epilogues via row-scale commutation
    bf16* gin = gA;
    bf16* gout = gB;
    for (int i = 0; i < 3; ++i) {
        const float* sin_p = (i == 0) ? nullptr : sumsq + (size_t)(i - 1) * 4096;
        gemm_bf16<MODE_RPE, bf16><<<dim3(4, 32), blk, 0, stream>>>(
            gin, Wl_bf + (size_t)i * ED * ED, bl + (size_t)i * ED, nullptr,
            gout, nullptr, 4096, ED, ED, sin_p, sumsq + (size_t)i * 4096);
        bf16* t = gin; gin = gout; gout = t;
    }
    gemm_bf16<MODE_AT, float><<<dim3(12, 32), blk, 0, stream>>>(
        gin, Wr_bf, br, nullptr, a_t, nullptr, 4096, D1, ED,
        sumsq + 2 * 4096, nullptr);

    fft_a_kernel<<<768, blk, 0, stream>>>(a_t, (cx*)Wspec);
    fft_conv_kernel<<<3072, blk, 0, stream>>>(
        v_t, (const cx*)Wspec, u_t, gated_t);

    transpose_cs_kernel<<<dim3(24, 128), blk, 0, stream>>>(gated_t, gated);

    gemm_bf16<MODE_PLAIN, float><<<dim3(4, 64), blk, 0, stream>>>(
        gated, Wo_bf, bo, nullptr, out, nullptr, 8192, ED, D1,
        nullptr, nullptr);
}